// Round 1
// baseline (5814.513 us; speedup 1.0000x reference)
//
#include <hip/hip_runtime.h>
#include <math.h>

// Problem constants (fixed by the reference)
constexpr int kN0 = 400000, kN1 = 100000, kN2 = 20000;
constexpr int kE1 = 1000000, kE2 = 200000;
constexpr int kIN = 128, kHID = 256, kOUT = 47;
constexpr float kEPS = 1e-5f, kNEG = 0.2f;

#define DEV static __device__ __forceinline__

// ---- ordered-uint encoding so atomicMax(unsigned) == float max ----
DEV unsigned f2ord(float f) {
    unsigned u = __float_as_uint(f);
    return (u & 0x80000000u) ? ~u : (u | 0x80000000u);
}
DEV float ord2f(unsigned u) {
    return (u & 0x80000000u) ? __uint_as_float(u & 0x7fffffffu) : __uint_as_float(~u);
}

// ---------------- utility fills ----------------
__global__ void zero_f32(float* __restrict__ p, int n) {
    int i = blockIdx.x * blockDim.x + threadIdx.x;
    int st = gridDim.x * blockDim.x;
    for (; i < n; i += st) p[i] = 0.f;
}
__global__ void fill_u32(unsigned* __restrict__ p, unsigned v, int n) {
    int i = blockIdx.x * blockDim.x + threadIdx.x;
    if (i < n) p[i] = v;
}

// ---------------- fp32 tiled GEMM: C[M,N] (+)= A[M,K] @ B[K,N] + bias1 + bias2 ----------------
// BM=BN=64, BK=32, 256 threads, 4x4 per thread. K must be a multiple of 32 (128 or 256 here).
template <bool ACCUM>
__global__ __launch_bounds__(256) void gemm64(const float* __restrict__ A,
                                              const float* __restrict__ B,
                                              float* __restrict__ Cmat,
                                              const float* __restrict__ bias1,
                                              const float* __restrict__ bias2,
                                              int M, int N, int K) {
    __shared__ float As[32][68];
    __shared__ float Bs[32][68];
    const int tid = threadIdx.x;
    const int tx = tid & 15, ty = tid >> 4;
    const int m0 = blockIdx.y * 64, n0 = blockIdx.x * 64;
    float acc[4][4] = {};

    for (int k0 = 0; k0 < K; k0 += 32) {
        // A tile: 64 rows x 32 k, transposed into As[k][row]
        #pragma unroll
        for (int t = 0; t < 2; ++t) {
            int i = tid + t * 256;     // 0..511
            int row = i >> 3;          // 0..63
            int kq = (i & 7) << 2;     // 0,4,...,28
            float4 v = make_float4(0.f, 0.f, 0.f, 0.f);
            int gr = m0 + row;
            if (gr < M) v = *reinterpret_cast<const float4*>(&A[(size_t)gr * K + k0 + kq]);
            As[kq + 0][row] = v.x; As[kq + 1][row] = v.y;
            As[kq + 2][row] = v.z; As[kq + 3][row] = v.w;
        }
        // B tile: 32 k x 64 cols
        if ((N & 3) == 0) {
            #pragma unroll
            for (int t = 0; t < 2; ++t) {
                int i = tid + t * 256;
                int kr = i >> 4;          // 0..31
                int cq = (i & 15) << 2;   // 0..60
                float4 v = make_float4(0.f, 0.f, 0.f, 0.f);
                int gc = n0 + cq;
                if (gc < N) v = *reinterpret_cast<const float4*>(&B[(size_t)(k0 + kr) * N + gc]);
                *reinterpret_cast<float4*>(&Bs[kr][cq]) = v;
            }
        } else {
            #pragma unroll
            for (int t = 0; t < 2; ++t) {
                int i = tid + t * 256;
                int kr = i >> 4;
                int cq = (i & 15) << 2;
                #pragma unroll
                for (int j = 0; j < 4; ++j) {
                    int gc = n0 + cq + j;
                    Bs[kr][cq + j] = (gc < N) ? B[(size_t)(k0 + kr) * N + gc] : 0.f;
                }
            }
        }
        __syncthreads();
        #pragma unroll
        for (int kk = 0; kk < 32; ++kk) {
            float4 a4 = *reinterpret_cast<const float4*>(&As[kk][ty << 2]);
            float4 b4 = *reinterpret_cast<const float4*>(&Bs[kk][tx << 2]);
            float a[4] = {a4.x, a4.y, a4.z, a4.w};
            float b[4] = {b4.x, b4.y, b4.z, b4.w};
            #pragma unroll
            for (int i2 = 0; i2 < 4; ++i2)
                #pragma unroll
                for (int j = 0; j < 4; ++j)
                    acc[i2][j] = fmaf(a[i2], b[j], acc[i2][j]);
        }
        __syncthreads();
    }

    #pragma unroll
    for (int i2 = 0; i2 < 4; ++i2) {
        int row = m0 + (ty << 2) + i2;
        if (row >= M) continue;
        #pragma unroll
        for (int j = 0; j < 4; ++j) {
            int col = n0 + (tx << 2) + j;
            if (col >= N) continue;
            float v = acc[i2][j];
            if (bias1) v += bias1[col];
            if (bias2) v += bias2[col];
            size_t idx = (size_t)row * N + col;
            if (ACCUM) v += Cmat[idx];
            Cmat[idx] = v;
        }
    }
}

// ---------------- attention logit dots: al_s[n,h] = <xp[n,h,:], a_src[h,:]>, al_d for n<Ndst ----------------
// one wave per node; lane = channel within head
__global__ __launch_bounds__(256) void attn_al(const float* __restrict__ xp,
                                               const float* __restrict__ a_src,
                                               const float* __restrict__ a_dst,
                                               float* __restrict__ als,
                                               float* __restrict__ ald,
                                               int N, int Ndst) {
    int wave = blockIdx.x * (blockDim.x >> 6) + (threadIdx.x >> 6);
    int lane = threadIdx.x & 63;
    if (wave >= N) return;
    const float* row = xp + (size_t)wave * 256;
    float ps[4], pd[4];
    #pragma unroll
    for (int h = 0; h < 4; ++h) {
        float v = row[h * 64 + lane];
        ps[h] = v * a_src[h * 64 + lane];
        pd[h] = v * a_dst[h * 64 + lane];
    }
    #pragma unroll
    for (int off = 32; off > 0; off >>= 1) {
        #pragma unroll
        for (int h = 0; h < 4; ++h) {
            ps[h] += __shfl_xor(ps[h], off, 64);
            pd[h] += __shfl_xor(pd[h], off, 64);
        }
    }
    if (lane == 0) {
        #pragma unroll
        for (int h = 0; h < 4; ++h) als[(size_t)wave * 4 + h] = ps[h];
        if (wave < Ndst) {
            #pragma unroll
            for (int h = 0; h < 4; ++h) ald[(size_t)wave * 4 + h] = pd[h];
        }
    }
}

// ---------------- edge pass A: logits + segment max ----------------
__global__ void edge_logit_max(const float* __restrict__ als, const float* __restrict__ ald,
                               const int* __restrict__ src, const int* __restrict__ dst,
                               float* __restrict__ elog, unsigned* __restrict__ mord, int E) {
    int e = blockIdx.x * blockDim.x + threadIdx.x;
    if (e >= E) return;
    int s = src[e], d = dst[e];
    float4 ls = *reinterpret_cast<const float4*>(&als[(size_t)s * 4]);
    float4 ld = *reinterpret_cast<const float4*>(&ald[(size_t)d * 4]);
    float l[4] = {ls.x + ld.x, ls.y + ld.y, ls.z + ld.z, ls.w + ld.w};
    #pragma unroll
    for (int h = 0; h < 4; ++h) {
        float v = l[h] >= 0.f ? l[h] : kNEG * l[h];
        l[h] = v;
        atomicMax(&mord[d * 4 + h], f2ord(v));
    }
    *reinterpret_cast<float4*>(&elog[(size_t)e * 4]) = make_float4(l[0], l[1], l[2], l[3]);
}

// decode ordered-uint max in place; -inf (no edges) -> 0
__global__ void decode_m(unsigned* __restrict__ p, int n) {
    int i = blockIdx.x * blockDim.x + threadIdx.x;
    if (i >= n) return;
    float f = ord2f(p[i]);
    if (f == -INFINITY) f = 0.f;
    reinterpret_cast<float*>(p)[i] = f;
}

// ---------------- edge pass B: e = exp(l - m[dst]) + segment sum ----------------
__global__ void edge_exp_sum(const float* __restrict__ m, const int* __restrict__ dst,
                             float* __restrict__ elog, float* __restrict__ ssum, int E) {
    int e = blockIdx.x * blockDim.x + threadIdx.x;
    if (e >= E) return;
    int d = dst[e];
    float4 l = *reinterpret_cast<const float4*>(&elog[(size_t)e * 4]);
    float4 mm = *reinterpret_cast<const float4*>(&m[(size_t)d * 4]);
    float v0 = expf(l.x - mm.x), v1 = expf(l.y - mm.y);
    float v2 = expf(l.z - mm.z), v3 = expf(l.w - mm.w);
    atomicAdd(&ssum[d * 4 + 0], v0);
    atomicAdd(&ssum[d * 4 + 1], v1);
    atomicAdd(&ssum[d * 4 + 2], v2);
    atomicAdd(&ssum[d * 4 + 3], v3);
    *reinterpret_cast<float4*>(&elog[(size_t)e * 4]) = make_float4(v0, v1, v2, v3);
}

// ---------------- edge pass B2: alpha = e / (s[dst] + 1e-16) ----------------
__global__ void edge_alpha(float* __restrict__ elog, const float* __restrict__ ssum,
                           const int* __restrict__ dst, int E) {
    int e = blockIdx.x * blockDim.x + threadIdx.x;
    if (e >= E) return;
    int d = dst[e];
    float4 v = *reinterpret_cast<const float4*>(&elog[(size_t)e * 4]);
    float4 s4 = *reinterpret_cast<const float4*>(&ssum[(size_t)d * 4]);
    v.x /= (s4.x + 1e-16f);
    v.y /= (s4.y + 1e-16f);
    v.z /= (s4.z + 1e-16f);
    v.w /= (s4.w + 1e-16f);
    *reinterpret_cast<float4*>(&elog[(size_t)e * 4]) = v;
}

// ---------------- edge pass C: out[dst] += alpha * xp[src]  (thread = edge x 4-channel group) ----------------
__global__ __launch_bounds__(256) void edge_aggregate(const float* __restrict__ xp,
                                                      const float* __restrict__ alpha,
                                                      const int* __restrict__ src,
                                                      const int* __restrict__ dst,
                                                      float* __restrict__ out, int E) {
    int gid = blockIdx.x * blockDim.x + threadIdx.x;
    if (gid >= E * 64) return;
    int e = gid >> 6;
    int g = gid & 63;               // 0..63 -> head = g>>4, float4 group
    int s = src[e], d = dst[e];
    float a = alpha[(size_t)e * 4 + (g >> 4)];
    float4 v = *reinterpret_cast<const float4*>(&xp[(size_t)s * 256 + (g << 2)]);
    float* o = &out[(size_t)d * 256 + (g << 2)];
    atomicAdd(o + 0, a * v.x);
    atomicAdd(o + 1, a * v.y);
    atomicAdd(o + 2, a * v.z);
    atomicAdd(o + 3, a * v.w);
}

// ---------------- BN stats: per-column sum & sumsq over M rows (HID=256 cols) ----------------
__global__ __launch_bounds__(256) void bn_stats(const float* __restrict__ X,
                                                float* __restrict__ stats, int M) {
    int c = threadIdx.x;
    float s = 0.f, sq = 0.f;
    for (int r = blockIdx.x; r < M; r += gridDim.x) {
        float v = X[(size_t)r * 256 + c];
        s += v;
        sq += v * v;
    }
    atomicAdd(&stats[c], s);
    atomicAdd(&stats[256 + c], sq);
}

// ---------------- BN apply + activation (0 = ELU, 1 = ReLU), in place ----------------
template <int ACT>
__global__ __launch_bounds__(256) void bn_apply(float* __restrict__ X,
                                                const float* __restrict__ stats,
                                                const float* __restrict__ gamma,
                                                const float* __restrict__ beta, int M) {
    int row = blockIdx.x;
    int c = threadIdx.x;
    float mu = stats[c] / (float)M;
    float var = stats[256 + c] / (float)M - mu * mu;
    float sc = rsqrtf(var + kEPS) * gamma[c];
    float sh = beta[c];
    size_t idx = (size_t)row * 256 + c;
    float v = (X[idx] - mu) * sc + sh;
    if (ACT == 0) v = v > 0.f ? v : expm1f(v);
    else v = fmaxf(v, 0.f);
    X[idx] = v;
}

extern "C" void kernel_launch(void* const* d_in, const int* in_sizes, int n_in,
                              void* d_out, int out_size, void* d_ws, size_t ws_size,
                              hipStream_t stream) {
    (void)in_sizes; (void)n_in; (void)out_size; (void)ws_size;

    const float* x      = (const float*)d_in[0];
    const int*   src1   = (const int*)d_in[1];
    const int*   dst1   = (const int*)d_in[2];
    const int*   src2   = (const int*)d_in[3];
    const int*   dst2   = (const int*)d_in[4];
    const float* W1     = (const float*)d_in[5];
    const float* a_src1 = (const float*)d_in[6];
    const float* a_dst1 = (const float*)d_in[7];
    const float* b1     = (const float*)d_in[8];
    const float* Wsk1   = (const float*)d_in[9];
    const float* bsk1   = (const float*)d_in[10];
    const float* g1     = (const float*)d_in[11];
    const float* be1    = (const float*)d_in[12];
    const float* W2     = (const float*)d_in[13];
    const float* a_src2 = (const float*)d_in[14];
    const float* a_dst2 = (const float*)d_in[15];
    const float* b2     = (const float*)d_in[16];
    const float* Wsk2   = (const float*)d_in[17];
    const float* bsk2   = (const float*)d_in[18];
    const float* g2     = (const float*)d_in[19];
    const float* be2    = (const float*)d_in[20];
    const float* Wm1    = (const float*)d_in[21];
    const float* bm1    = (const float*)d_in[22];
    const float* gm     = (const float*)d_in[23];
    const float* bem    = (const float*)d_in[24];
    const float* Wm2    = (const float*)d_in[25];
    const float* bm2    = (const float*)d_in[26];

    // ---- workspace layout (floats); total ~146.5M floats = ~586 MB ----
    float* ws = (float*)d_ws;
    size_t off = 0;
    auto alloc = [&](size_t n) { float* p = ws + off; off += n; return p; };
    float* xp1   = alloc((size_t)kN0 * 256);   // 102.4M ; reused as xp2 after layer 1
    float* h1    = alloc((size_t)kN1 * 256);   // 25.6M
    float* h2    = alloc((size_t)kN2 * 256);   // 5.12M
    float* h3    = alloc((size_t)kN2 * 256);   // 5.12M
    float* als1  = alloc((size_t)kN0 * 4);
    float* ald1  = alloc((size_t)kN1 * 4);
    float* elog1 = alloc((size_t)kE1 * 4);
    float* m1    = alloc((size_t)kN1 * 4);
    float* s1b   = alloc((size_t)kN1 * 4);
    float* als2  = alloc((size_t)kN1 * 4);
    float* ald2  = alloc((size_t)kN2 * 4);
    float* elog2 = alloc((size_t)kE2 * 4);
    float* m2    = alloc((size_t)kN2 * 4);
    float* s2b   = alloc((size_t)kN2 * 4);
    float* stats = alloc(1536);                 // 3 x (sum[256], sumsq[256])
    float* stats1 = stats, *stats2 = stats + 512, *stats3 = stats + 1024;
    float* xp2 = xp1;

    hipStream_t st = stream;

    // ---- init accumulators (every call; graph replays re-run these) ----
    zero_f32<<<2048, 256, 0, st>>>(h1, kN1 * 256);
    zero_f32<<<512, 256, 0, st>>>(h2, kN2 * 256);
    zero_f32<<<256, 256, 0, st>>>(s1b, kN1 * 4);
    zero_f32<<<64, 256, 0, st>>>(s2b, kN2 * 4);
    zero_f32<<<6, 256, 0, st>>>(stats, 1536);
    fill_u32<<<(kN1 * 4 + 255) / 256, 256, 0, st>>>((unsigned*)m1, 0x007FFFFFu, kN1 * 4); // ord(-inf)
    fill_u32<<<(kN2 * 4 + 255) / 256, 256, 0, st>>>((unsigned*)m2, 0x007FFFFFu, kN2 * 4);

    // ================= layer 1 =================
    gemm64<false><<<dim3(4, (kN0 + 63) / 64), 256, 0, st>>>(x, W1, xp1, nullptr, nullptr, kN0, 256, kIN);
    attn_al<<<kN0 / 4, 256, 0, st>>>(xp1, a_src1, a_dst1, als1, ald1, kN0, kN1);
    edge_logit_max<<<(kE1 + 255) / 256, 256, 0, st>>>(als1, ald1, src1, dst1, elog1, (unsigned*)m1, kE1);
    decode_m<<<(kN1 * 4 + 255) / 256, 256, 0, st>>>((unsigned*)m1, kN1 * 4);
    edge_exp_sum<<<(kE1 + 255) / 256, 256, 0, st>>>(m1, dst1, elog1, s1b, kE1);
    edge_alpha<<<(kE1 + 255) / 256, 256, 0, st>>>(elog1, s1b, dst1, kE1);
    edge_aggregate<<<(kE1 * 64 + 255) / 256, 256, 0, st>>>(xp1, elog1, src1, dst1, h1, kE1);
    gemm64<true><<<dim3(4, (kN1 + 63) / 64), 256, 0, st>>>(x, Wsk1, h1, b1, bsk1, kN1, 256, kIN);
    bn_stats<<<256, 256, 0, st>>>(h1, stats1, kN1);
    bn_apply<0><<<kN1, 256, 0, st>>>(h1, stats1, g1, be1, kN1);

    // ================= layer 2 =================
    gemm64<false><<<dim3(4, (kN1 + 63) / 64), 256, 0, st>>>(h1, W2, xp2, nullptr, nullptr, kN1, 256, kHID);
    attn_al<<<kN1 / 4, 256, 0, st>>>(xp2, a_src2, a_dst2, als2, ald2, kN1, kN2);
    edge_logit_max<<<(kE2 + 255) / 256, 256, 0, st>>>(als2, ald2, src2, dst2, elog2, (unsigned*)m2, kE2);
    decode_m<<<(kN2 * 4 + 255) / 256, 256, 0, st>>>((unsigned*)m2, kN2 * 4);
    edge_exp_sum<<<(kE2 + 255) / 256, 256, 0, st>>>(m2, dst2, elog2, s2b, kE2);
    edge_alpha<<<(kE2 + 255) / 256, 256, 0, st>>>(elog2, s2b, dst2, kE2);
    edge_aggregate<<<(kE2 * 64 + 255) / 256, 256, 0, st>>>(xp2, elog2, src2, dst2, h2, kE2);
    gemm64<true><<<dim3(4, (kN2 + 63) / 64), 256, 0, st>>>(h1, Wsk2, h2, b2, bsk2, kN2, 256, kHID);
    bn_stats<<<256, 256, 0, st>>>(h2, stats2, kN2);
    bn_apply<0><<<kN2, 256, 0, st>>>(h2, stats2, g2, be2, kN2);

    // ================= MLP head =================
    gemm64<false><<<dim3(4, (kN2 + 63) / 64), 256, 0, st>>>(h2, Wm1, h3, bm1, nullptr, kN2, 256, kHID);
    bn_stats<<<256, 256, 0, st>>>(h3, stats3, kN2);
    bn_apply<1><<<kN2, 256, 0, st>>>(h3, stats3, gm, bem, kN2);
    gemm64<false><<<dim3(1, (kN2 + 63) / 64), 256, 0, st>>>(h3, Wm2, (float*)d_out, bm2, nullptr, kN2, kOUT, kHID);
}

// Round 2
// 2195.429 us; speedup vs baseline: 2.6485x; 2.6485x over previous
//
#include <hip/hip_runtime.h>
#include <math.h>

// Problem constants (fixed by the reference)
constexpr int kN0 = 400000, kN1 = 100000, kN2 = 20000;
constexpr int kE1 = 1000000, kE2 = 200000;
constexpr int kIN = 128, kHID = 256, kOUT = 47;
constexpr float kEPS = 1e-5f, kNEG = 0.2f;

#define DEV static __device__ __forceinline__

// ---- ordered-uint encoding so atomicMax(unsigned) == float max ----
DEV unsigned f2ord(float f) {
    unsigned u = __float_as_uint(f);
    return (u & 0x80000000u) ? ~u : (u | 0x80000000u);
}
DEV float ord2f(unsigned u) {
    return (u & 0x80000000u) ? __uint_as_float(u & 0x7fffffffu) : __uint_as_float(~u);
}

// ---------------- utility fills ----------------
__global__ void zero_f32(float* __restrict__ p, int n) {
    int i = blockIdx.x * blockDim.x + threadIdx.x;
    int st = gridDim.x * blockDim.x;
    for (; i < n; i += st) p[i] = 0.f;
}
__global__ void fill_u32(unsigned* __restrict__ p, unsigned v, int n) {
    int i = blockIdx.x * blockDim.x + threadIdx.x;
    if (i < n) p[i] = v;
}

// ================= CSR build (per call; graph-capture safe) =================
__global__ void hist_dst(const int* __restrict__ dst, int* __restrict__ counts, int E) {
    int e = blockIdx.x * blockDim.x + threadIdx.x;
    if (e < E) atomicAdd(&counts[dst[e]], 1);
}

// block-level exclusive scan: 256 threads x 4 items = 1024/block
__global__ __launch_bounds__(256) void scan_block(const int* __restrict__ counts, int n,
                                                  int* __restrict__ offs, int* __restrict__ bsum) {
    __shared__ int sh[256];
    int tid = threadIdx.x;
    int base = blockIdx.x * 1024 + tid * 4;
    int c0 = (base + 0 < n) ? counts[base + 0] : 0;
    int c1 = (base + 1 < n) ? counts[base + 1] : 0;
    int c2 = (base + 2 < n) ? counts[base + 2] : 0;
    int c3 = (base + 3 < n) ? counts[base + 3] : 0;
    int tot = c0 + c1 + c2 + c3;
    sh[tid] = tot;
    __syncthreads();
    for (int o = 1; o < 256; o <<= 1) {
        int t = (tid >= o) ? sh[tid - o] : 0;
        __syncthreads();
        sh[tid] += t;
        __syncthreads();
    }
    int excl = sh[tid] - tot;
    if (base + 0 < n) offs[base + 0] = excl;
    if (base + 1 < n) offs[base + 1] = excl + c0;
    if (base + 2 < n) offs[base + 2] = excl + c0 + c1;
    if (base + 3 < n) offs[base + 3] = excl + c0 + c1 + c2;
    if (tid == 255) bsum[blockIdx.x] = sh[255];
}

// scan the per-block sums (nb <= 256) into exclusive bscan
__global__ __launch_bounds__(256) void scan_bsums(const int* __restrict__ bsum,
                                                  int* __restrict__ bscan, int nb) {
    __shared__ int sh[256];
    int tid = threadIdx.x;
    int v = (tid < nb) ? bsum[tid] : 0;
    sh[tid] = v;
    __syncthreads();
    for (int o = 1; o < 256; o <<= 1) {
        int t = (tid >= o) ? sh[tid - o] : 0;
        __syncthreads();
        sh[tid] += t;
        __syncthreads();
    }
    if (tid < nb) bscan[tid] = sh[tid] - v;
}

__global__ void scan_add(int* __restrict__ offs, const int* __restrict__ bscan,
                         const int* __restrict__ counts, int n) {
    int i = blockIdx.x * blockDim.x + threadIdx.x;
    if (i < n) {
        int v = offs[i] + bscan[i >> 10];
        offs[i] = v;
        if (i == n - 1) offs[n] = v + counts[i];
    }
}

__global__ void csr_scatter(const int* __restrict__ dst, const int* __restrict__ offs,
                            int* __restrict__ cur, int* __restrict__ eid, int E) {
    int e = blockIdx.x * blockDim.x + threadIdx.x;
    if (e >= E) return;
    int d = dst[e];
    int pos = offs[d] + atomicAdd(&cur[d], 1);
    eid[pos] = e;
}

// ---------------- fp32 tiled GEMM: C[M,N] (+)= A[M,K] @ B[K,N] + bias1 + bias2 ----------------
template <bool ACCUM>
__global__ __launch_bounds__(256) void gemm64(const float* __restrict__ A,
                                              const float* __restrict__ B,
                                              float* __restrict__ Cmat,
                                              const float* __restrict__ bias1,
                                              const float* __restrict__ bias2,
                                              int M, int N, int K) {
    __shared__ float As[32][68];
    __shared__ float Bs[32][68];
    const int tid = threadIdx.x;
    const int tx = tid & 15, ty = tid >> 4;
    const int m0 = blockIdx.y * 64, n0 = blockIdx.x * 64;
    float acc[4][4] = {};

    for (int k0 = 0; k0 < K; k0 += 32) {
        #pragma unroll
        for (int t = 0; t < 2; ++t) {
            int i = tid + t * 256;
            int row = i >> 3;
            int kq = (i & 7) << 2;
            float4 v = make_float4(0.f, 0.f, 0.f, 0.f);
            int gr = m0 + row;
            if (gr < M) v = *reinterpret_cast<const float4*>(&A[(size_t)gr * K + k0 + kq]);
            As[kq + 0][row] = v.x; As[kq + 1][row] = v.y;
            As[kq + 2][row] = v.z; As[kq + 3][row] = v.w;
        }
        if ((N & 3) == 0) {
            #pragma unroll
            for (int t = 0; t < 2; ++t) {
                int i = tid + t * 256;
                int kr = i >> 4;
                int cq = (i & 15) << 2;
                float4 v = make_float4(0.f, 0.f, 0.f, 0.f);
                int gc = n0 + cq;
                if (gc < N) v = *reinterpret_cast<const float4*>(&B[(size_t)(k0 + kr) * N + gc]);
                *reinterpret_cast<float4*>(&Bs[kr][cq]) = v;
            }
        } else {
            #pragma unroll
            for (int t = 0; t < 2; ++t) {
                int i = tid + t * 256;
                int kr = i >> 4;
                int cq = (i & 15) << 2;
                #pragma unroll
                for (int j = 0; j < 4; ++j) {
                    int gc = n0 + cq + j;
                    Bs[kr][cq + j] = (gc < N) ? B[(size_t)(k0 + kr) * N + gc] : 0.f;
                }
            }
        }
        __syncthreads();
        #pragma unroll
        for (int kk = 0; kk < 32; ++kk) {
            float4 a4 = *reinterpret_cast<const float4*>(&As[kk][ty << 2]);
            float4 b4 = *reinterpret_cast<const float4*>(&Bs[kk][tx << 2]);
            float a[4] = {a4.x, a4.y, a4.z, a4.w};
            float b[4] = {b4.x, b4.y, b4.z, b4.w};
            #pragma unroll
            for (int i2 = 0; i2 < 4; ++i2)
                #pragma unroll
                for (int j = 0; j < 4; ++j)
                    acc[i2][j] = fmaf(a[i2], b[j], acc[i2][j]);
        }
        __syncthreads();
    }

    #pragma unroll
    for (int i2 = 0; i2 < 4; ++i2) {
        int row = m0 + (ty << 2) + i2;
        if (row >= M) continue;
        #pragma unroll
        for (int j = 0; j < 4; ++j) {
            int col = n0 + (tx << 2) + j;
            if (col >= N) continue;
            float v = acc[i2][j];
            if (bias1) v += bias1[col];
            if (bias2) v += bias2[col];
            size_t idx = (size_t)row * N + col;
            if (ACCUM) v += Cmat[idx];
            Cmat[idx] = v;
        }
    }
}

// ---------------- attention logit dots ----------------
__global__ __launch_bounds__(256) void attn_al(const float* __restrict__ xp,
                                               const float* __restrict__ a_src,
                                               const float* __restrict__ a_dst,
                                               float* __restrict__ als,
                                               float* __restrict__ ald,
                                               int N, int Ndst) {
    int wave = blockIdx.x * (blockDim.x >> 6) + (threadIdx.x >> 6);
    int lane = threadIdx.x & 63;
    if (wave >= N) return;
    const float* row = xp + (size_t)wave * 256;
    float ps[4], pd[4];
    #pragma unroll
    for (int h = 0; h < 4; ++h) {
        float v = row[h * 64 + lane];
        ps[h] = v * a_src[h * 64 + lane];
        pd[h] = v * a_dst[h * 64 + lane];
    }
    #pragma unroll
    for (int off = 32; off > 0; off >>= 1) {
        #pragma unroll
        for (int h = 0; h < 4; ++h) {
            ps[h] += __shfl_xor(ps[h], off, 64);
            pd[h] += __shfl_xor(pd[h], off, 64);
        }
    }
    if (lane == 0) {
        #pragma unroll
        for (int h = 0; h < 4; ++h) als[(size_t)wave * 4 + h] = ps[h];
        if (wave < Ndst) {
            #pragma unroll
            for (int h = 0; h < 4; ++h) ald[(size_t)wave * 4 + h] = pd[h];
        }
    }
}

// ---------------- edge pass A: logits + segment max (atomic ordered-uint) ----------------
__global__ void edge_logit_max(const float* __restrict__ als, const float* __restrict__ ald,
                               const int* __restrict__ src, const int* __restrict__ dst,
                               float* __restrict__ elog, unsigned* __restrict__ mord, int E) {
    int e = blockIdx.x * blockDim.x + threadIdx.x;
    if (e >= E) return;
    int s = src[e], d = dst[e];
    float4 ls = *reinterpret_cast<const float4*>(&als[(size_t)s * 4]);
    float4 ld = *reinterpret_cast<const float4*>(&ald[(size_t)d * 4]);
    float l[4] = {ls.x + ld.x, ls.y + ld.y, ls.z + ld.z, ls.w + ld.w};
    #pragma unroll
    for (int h = 0; h < 4; ++h) {
        float v = l[h] >= 0.f ? l[h] : kNEG * l[h];
        l[h] = v;
        atomicMax(&mord[d * 4 + h], f2ord(v));
    }
    *reinterpret_cast<float4*>(&elog[(size_t)e * 4]) = make_float4(l[0], l[1], l[2], l[3]);
}

__global__ void decode_m(unsigned* __restrict__ p, int n) {
    int i = blockIdx.x * blockDim.x + threadIdx.x;
    if (i >= n) return;
    float f = ord2f(p[i]);
    if (f == -INFINITY) f = 0.f;
    reinterpret_cast<float*>(p)[i] = f;
}

// ---------------- edge pass B: e = exp(l - m[dst]) + segment sum ----------------
__global__ void edge_exp_sum(const float* __restrict__ m, const int* __restrict__ dst,
                             float* __restrict__ elog, float* __restrict__ ssum, int E) {
    int e = blockIdx.x * blockDim.x + threadIdx.x;
    if (e >= E) return;
    int d = dst[e];
    float4 l = *reinterpret_cast<const float4*>(&elog[(size_t)e * 4]);
    float4 mm = *reinterpret_cast<const float4*>(&m[(size_t)d * 4]);
    float v0 = expf(l.x - mm.x), v1 = expf(l.y - mm.y);
    float v2 = expf(l.z - mm.z), v3 = expf(l.w - mm.w);
    atomicAdd(&ssum[d * 4 + 0], v0);
    atomicAdd(&ssum[d * 4 + 1], v1);
    atomicAdd(&ssum[d * 4 + 2], v2);
    atomicAdd(&ssum[d * 4 + 3], v3);
    *reinterpret_cast<float4*>(&elog[(size_t)e * 4]) = make_float4(v0, v1, v2, v3);
}

// ---------------- CSR aggregate: one wave per dst; alpha = e/(s+1e-16) fused ----------------
__global__ __launch_bounds__(256) void csr_aggregate(const float* __restrict__ xp,
                                                     const float* __restrict__ evals,
                                                     const float* __restrict__ ssum,
                                                     const int* __restrict__ src,
                                                     const int* __restrict__ offs,
                                                     const int* __restrict__ eid,
                                                     float* __restrict__ out, int Ndst) {
    int d = blockIdx.x * 4 + (threadIdx.x >> 6);
    if (d >= Ndst) return;
    int lane = threadIdx.x & 63;
    int h = lane >> 4;
    int beg = offs[d], end = offs[d + 1];
    float inv = 1.f / (ssum[(size_t)d * 4 + h] + 1e-16f);
    float4 acc = make_float4(0.f, 0.f, 0.f, 0.f);
    for (int i = beg; i < end; ++i) {
        int e = eid[i];
        float a = evals[(size_t)e * 4 + h] * inv;
        int s = src[e];
        float4 v = *reinterpret_cast<const float4*>(&xp[(size_t)s * 256 + (lane << 2)]);
        acc.x = fmaf(a, v.x, acc.x);
        acc.y = fmaf(a, v.y, acc.y);
        acc.z = fmaf(a, v.z, acc.z);
        acc.w = fmaf(a, v.w, acc.w);
    }
    *reinterpret_cast<float4*>(&out[(size_t)d * 256 + (lane << 2)]) = acc;
}

// ---------------- BN stats & apply ----------------
__global__ __launch_bounds__(256) void bn_stats(const float* __restrict__ X,
                                                float* __restrict__ stats, int M) {
    int c = threadIdx.x;
    float s = 0.f, sq = 0.f;
    for (int r = blockIdx.x; r < M; r += gridDim.x) {
        float v = X[(size_t)r * 256 + c];
        s += v;
        sq += v * v;
    }
    atomicAdd(&stats[c], s);
    atomicAdd(&stats[256 + c], sq);
}

template <int ACT>
__global__ __launch_bounds__(256) void bn_apply(float* __restrict__ X,
                                                const float* __restrict__ stats,
                                                const float* __restrict__ gamma,
                                                const float* __restrict__ beta, int M) {
    int row = blockIdx.x;
    int c = threadIdx.x;
    float mu = stats[c] / (float)M;
    float var = stats[256 + c] / (float)M - mu * mu;
    float sc = rsqrtf(var + kEPS) * gamma[c];
    float sh = beta[c];
    size_t idx = (size_t)row * 256 + c;
    float v = (X[idx] - mu) * sc + sh;
    if (ACT == 0) v = v > 0.f ? v : expm1f(v);
    else v = fmaxf(v, 0.f);
    X[idx] = v;
}

extern "C" void kernel_launch(void* const* d_in, const int* in_sizes, int n_in,
                              void* d_out, int out_size, void* d_ws, size_t ws_size,
                              hipStream_t stream) {
    (void)in_sizes; (void)n_in; (void)out_size; (void)ws_size;

    const float* x      = (const float*)d_in[0];
    const int*   src1   = (const int*)d_in[1];
    const int*   dst1   = (const int*)d_in[2];
    const int*   src2   = (const int*)d_in[3];
    const int*   dst2   = (const int*)d_in[4];
    const float* W1     = (const float*)d_in[5];
    const float* a_src1 = (const float*)d_in[6];
    const float* a_dst1 = (const float*)d_in[7];
    const float* b1     = (const float*)d_in[8];
    const float* Wsk1   = (const float*)d_in[9];
    const float* bsk1   = (const float*)d_in[10];
    const float* g1     = (const float*)d_in[11];
    const float* be1    = (const float*)d_in[12];
    const float* W2     = (const float*)d_in[13];
    const float* a_src2 = (const float*)d_in[14];
    const float* a_dst2 = (const float*)d_in[15];
    const float* b2     = (const float*)d_in[16];
    const float* Wsk2   = (const float*)d_in[17];
    const float* bsk2   = (const float*)d_in[18];
    const float* g2     = (const float*)d_in[19];
    const float* be2    = (const float*)d_in[20];
    const float* Wm1    = (const float*)d_in[21];
    const float* bm1    = (const float*)d_in[22];
    const float* gm     = (const float*)d_in[23];
    const float* bem    = (const float*)d_in[24];
    const float* Wm2    = (const float*)d_in[25];
    const float* bm2    = (const float*)d_in[26];

    // ---- workspace layout ----
    float* ws = (float*)d_ws;
    size_t off = 0;
    auto alloc = [&](size_t n) { float* p = ws + off; off += n; return p; };
    float* xp1   = alloc((size_t)kN0 * 256);   // reused as xp2 after layer 1
    float* h1    = alloc((size_t)kN1 * 256);
    float* h2    = alloc((size_t)kN2 * 256);
    float* h3    = alloc((size_t)kN2 * 256);
    float* als1  = alloc((size_t)kN0 * 4);
    float* ald1  = alloc((size_t)kN1 * 4);
    float* elog1 = alloc((size_t)kE1 * 4);
    float* m1    = alloc((size_t)kN1 * 4);
    float* s1b   = alloc((size_t)kN1 * 4);
    float* als2  = alloc((size_t)kN1 * 4);
    float* ald2  = alloc((size_t)kN2 * 4);
    float* elog2 = alloc((size_t)kE2 * 4);
    float* m2    = alloc((size_t)kN2 * 4);
    float* s2b   = alloc((size_t)kN2 * 4);
    float* stats = alloc(1536);
    float* stats1 = stats, *stats2 = stats + 512, *stats3 = stats + 1024;
    // CSR arrays (int)
    int* eid1   = (int*)alloc(kE1);
    int* offs1  = (int*)alloc(kN1 + 1);
    int* cnt1   = (int*)alloc(kN1);          // counts, then reused as scatter cursor
    int* bsum1  = (int*)alloc(128);
    int* bscan1 = (int*)alloc(128);
    int* eid2   = (int*)alloc(kE2);
    int* offs2  = (int*)alloc(kN2 + 1);
    int* cnt2   = (int*)alloc(kN2);
    int* bsum2  = (int*)alloc(128);
    int* bscan2 = (int*)alloc(128);
    float* xp2 = xp1;

    hipStream_t st = stream;
    const int nb1 = (kN1 + 1023) / 1024;   // 98
    const int nb2 = (kN2 + 1023) / 1024;   // 20

    // ---- init accumulators ----
    zero_f32<<<256, 256, 0, st>>>(s1b, kN1 * 4);
    zero_f32<<<64, 256, 0, st>>>(s2b, kN2 * 4);
    zero_f32<<<6, 256, 0, st>>>(stats, 1536);
    zero_f32<<<(kN1 + 255) / 256, 256, 0, st>>>((float*)cnt1, kN1);
    zero_f32<<<(kN2 + 255) / 256, 256, 0, st>>>((float*)cnt2, kN2);
    fill_u32<<<(kN1 * 4 + 255) / 256, 256, 0, st>>>((unsigned*)m1, 0x007FFFFFu, kN1 * 4);
    fill_u32<<<(kN2 * 4 + 255) / 256, 256, 0, st>>>((unsigned*)m2, 0x007FFFFFu, kN2 * 4);

    // ---- CSR build, layer 1 ----
    hist_dst<<<(kE1 + 255) / 256, 256, 0, st>>>(dst1, cnt1, kE1);
    scan_block<<<nb1, 256, 0, st>>>(cnt1, kN1, offs1, bsum1);
    scan_bsums<<<1, 256, 0, st>>>(bsum1, bscan1, nb1);
    scan_add<<<(kN1 + 255) / 256, 256, 0, st>>>(offs1, bscan1, cnt1, kN1);
    zero_f32<<<(kN1 + 255) / 256, 256, 0, st>>>((float*)cnt1, kN1);
    csr_scatter<<<(kE1 + 255) / 256, 256, 0, st>>>(dst1, offs1, cnt1, eid1, kE1);

    // ---- CSR build, layer 2 ----
    hist_dst<<<(kE2 + 255) / 256, 256, 0, st>>>(dst2, cnt2, kE2);
    scan_block<<<nb2, 256, 0, st>>>(cnt2, kN2, offs2, bsum2);
    scan_bsums<<<1, 256, 0, st>>>(bsum2, bscan2, nb2);
    scan_add<<<(kN2 + 255) / 256, 256, 0, st>>>(offs2, bscan2, cnt2, kN2);
    zero_f32<<<(kN2 + 255) / 256, 256, 0, st>>>((float*)cnt2, kN2);
    csr_scatter<<<(kE2 + 255) / 256, 256, 0, st>>>(dst2, offs2, cnt2, eid2, kE2);

    // ================= layer 1 =================
    gemm64<false><<<dim3(4, (kN0 + 63) / 64), 256, 0, st>>>(x, W1, xp1, nullptr, nullptr, kN0, 256, kIN);
    attn_al<<<kN0 / 4, 256, 0, st>>>(xp1, a_src1, a_dst1, als1, ald1, kN0, kN1);
    edge_logit_max<<<(kE1 + 255) / 256, 256, 0, st>>>(als1, ald1, src1, dst1, elog1, (unsigned*)m1, kE1);
    decode_m<<<(kN1 * 4 + 255) / 256, 256, 0, st>>>((unsigned*)m1, kN1 * 4);
    edge_exp_sum<<<(kE1 + 255) / 256, 256, 0, st>>>(m1, dst1, elog1, s1b, kE1);
    csr_aggregate<<<(kN1 + 3) / 4, 256, 0, st>>>(xp1, elog1, s1b, src1, offs1, eid1, h1, kN1);
    gemm64<true><<<dim3(4, (kN1 + 63) / 64), 256, 0, st>>>(x, Wsk1, h1, b1, bsk1, kN1, 256, kIN);
    bn_stats<<<256, 256, 0, st>>>(h1, stats1, kN1);
    bn_apply<0><<<kN1, 256, 0, st>>>(h1, stats1, g1, be1, kN1);

    // ================= layer 2 =================
    gemm64<false><<<dim3(4, (kN1 + 63) / 64), 256, 0, st>>>(h1, W2, xp2, nullptr, nullptr, kN1, 256, kHID);
    attn_al<<<kN1 / 4, 256, 0, st>>>(xp2, a_src2, a_dst2, als2, ald2, kN1, kN2);
    edge_logit_max<<<(kE2 + 255) / 256, 256, 0, st>>>(als2, ald2, src2, dst2, elog2, (unsigned*)m2, kE2);
    decode_m<<<(kN2 * 4 + 255) / 256, 256, 0, st>>>((unsigned*)m2, kN2 * 4);
    edge_exp_sum<<<(kE2 + 255) / 256, 256, 0, st>>>(m2, dst2, elog2, s2b, kE2);
    csr_aggregate<<<(kN2 + 3) / 4, 256, 0, st>>>(xp2, elog2, s2b, src2, offs2, eid2, h2, kN2);
    gemm64<true><<<dim3(4, (kN2 + 63) / 64), 256, 0, st>>>(h1, Wsk2, h2, b2, bsk2, kN2, 256, kHID);
    bn_stats<<<256, 256, 0, st>>>(h2, stats2, kN2);
    bn_apply<0><<<kN2, 256, 0, st>>>(h2, stats2, g2, be2, kN2);

    // ================= MLP head =================
    gemm64<false><<<dim3(4, (kN2 + 63) / 64), 256, 0, st>>>(h2, Wm1, h3, bm1, nullptr, kN2, 256, kHID);
    bn_stats<<<256, 256, 0, st>>>(h3, stats3, kN2);
    bn_apply<1><<<kN2, 256, 0, st>>>(h3, stats3, gm, bem, kN2);
    gemm64<false><<<dim3(1, (kN2 + 63) / 64), 256, 0, st>>>(h3, Wm2, (float*)d_out, bm2, nullptr, kN2, kOUT, kHID);
}

// Round 4
// 1598.941 us; speedup vs baseline: 3.6365x; 1.3731x over previous
//
#include <hip/hip_runtime.h>
#include <math.h>

// Problem constants (fixed by the reference)
constexpr int kN0 = 400000, kN1 = 100000, kN2 = 20000;
constexpr int kE1 = 1000000, kE2 = 200000;
constexpr int kIN = 128, kHID = 256, kOUT = 47;
constexpr float kEPS = 1e-5f, kNEG = 0.2f;

#define DEV static __device__ __forceinline__

typedef __attribute__((ext_vector_type(8))) short short8;
typedef __attribute__((ext_vector_type(4))) float f32x4;

DEV float b2f(unsigned short u) { return __uint_as_float(((unsigned)u) << 16); }
DEV unsigned short f2bf(float f) {
    unsigned u = __float_as_uint(f);
    unsigned r = (u + 0x7fffu + ((u >> 16) & 1u)) >> 16;   // RNE
    return (unsigned short)r;
}

DEV void gload_lds16(const void* g, void* l) {
    __builtin_amdgcn_global_load_lds(
        (const __attribute__((address_space(1))) void*)g,
        (__attribute__((address_space(3))) void*)l, 16, 0, 0);
}

// ---------------- utility ----------------
__global__ void zero_f32(float* __restrict__ p, int n) {
    int i = blockIdx.x * blockDim.x + threadIdx.x;
    int st = gridDim.x * blockDim.x;
    for (; i < n; i += st) p[i] = 0.f;
}

// f32 -> bf16 bulk convert (n multiple of 8)
__global__ void conv_bf16(const float* __restrict__ in, unsigned short* __restrict__ out, int n) {
    int i = (blockIdx.x * blockDim.x + threadIdx.x) * 8;
    if (i >= n) return;
    float4 v0 = *reinterpret_cast<const float4*>(&in[i]);
    float4 v1 = *reinterpret_cast<const float4*>(&in[i + 4]);
    ushort4 o0, o1;
    o0.x = f2bf(v0.x); o0.y = f2bf(v0.y); o0.z = f2bf(v0.z); o0.w = f2bf(v0.w);
    o1.x = f2bf(v1.x); o1.y = f2bf(v1.y); o1.z = f2bf(v1.z); o1.w = f2bf(v1.w);
    *reinterpret_cast<ushort4*>(&out[i]) = o0;
    *reinterpret_cast<ushort4*>(&out[i + 4]) = o1;
}

// W[K][N] f32 -> Wt[N][K] bf16 (tiny weight matrices)
__global__ void transp_w(const float* __restrict__ W, unsigned short* __restrict__ Wt, int K, int N) {
    int n = blockIdx.x * blockDim.x + threadIdx.x;
    if (n >= N) return;
    for (int k = 0; k < K; ++k) Wt[(size_t)n * K + k] = f2bf(W[(size_t)k * N + n]);
}

// ================= CSR build =================
__global__ void hist_dst(const int* __restrict__ dst, int* __restrict__ counts, int E) {
    int e = blockIdx.x * blockDim.x + threadIdx.x;
    if (e < E) atomicAdd(&counts[dst[e]], 1);
}

__global__ __launch_bounds__(256) void scan_block(const int* __restrict__ counts, int n,
                                                  int* __restrict__ offs, int* __restrict__ bsum) {
    __shared__ int sh[256];
    int tid = threadIdx.x;
    int base = blockIdx.x * 1024 + tid * 4;
    int c0 = (base + 0 < n) ? counts[base + 0] : 0;
    int c1 = (base + 1 < n) ? counts[base + 1] : 0;
    int c2 = (base + 2 < n) ? counts[base + 2] : 0;
    int c3 = (base + 3 < n) ? counts[base + 3] : 0;
    int tot = c0 + c1 + c2 + c3;
    sh[tid] = tot;
    __syncthreads();
    for (int o = 1; o < 256; o <<= 1) {
        int t = (tid >= o) ? sh[tid - o] : 0;
        __syncthreads();
        sh[tid] += t;
        __syncthreads();
    }
    int excl = sh[tid] - tot;
    if (base + 0 < n) offs[base + 0] = excl;
    if (base + 1 < n) offs[base + 1] = excl + c0;
    if (base + 2 < n) offs[base + 2] = excl + c0 + c1;
    if (base + 3 < n) offs[base + 3] = excl + c0 + c1 + c2;
    if (tid == 255) bsum[blockIdx.x] = sh[255];
}

__global__ __launch_bounds__(256) void scan_bsums(const int* __restrict__ bsum,
                                                  int* __restrict__ bscan, int nb) {
    __shared__ int sh[256];
    int tid = threadIdx.x;
    int v = (tid < nb) ? bsum[tid] : 0;
    sh[tid] = v;
    __syncthreads();
    for (int o = 1; o < 256; o <<= 1) {
        int t = (tid >= o) ? sh[tid - o] : 0;
        __syncthreads();
        sh[tid] += t;
        __syncthreads();
    }
    if (tid < nb) bscan[tid] = sh[tid] - v;
}

__global__ void scan_add(int* __restrict__ offs, const int* __restrict__ bscan,
                         const int* __restrict__ counts, int n) {
    int i = blockIdx.x * blockDim.x + threadIdx.x;
    if (i < n) {
        int v = offs[i] + bscan[i >> 10];
        offs[i] = v;
        if (i == n - 1) offs[n] = v + counts[i];
    }
}

__global__ void csr_scatter(const int* __restrict__ dst, const int* __restrict__ offs,
                            int* __restrict__ cur, int* __restrict__ eid, int E) {
    int e = blockIdx.x * blockDim.x + threadIdx.x;
    if (e >= E) return;
    int d = dst[e];
    int pos = offs[d] + atomicAdd(&cur[d], 1);
    eid[pos] = e;
}

// ================= bf16 MFMA GEMM =================
// C[M][N] (+)= A[M][K]bf16 @ Bt[N][K]bf16^T (+ bias1 + bias2), f32 math.
// BM=BN=128, BK=64, 256 threads = 4 waves (2x2), each wave 64x64 (4x4 frags of 16x16x32).
// LDS: linear [row][128B] tiles, XOR-swizzled k-slots via pre-swizzled global source (rule #21).
template <bool OUTBF, bool ACCUM>
__global__ __launch_bounds__(256) void mfma_gemm_bt(const unsigned short* __restrict__ A,
                                                    const unsigned short* __restrict__ Bt,
                                                    void* __restrict__ Cv,
                                                    const float* __restrict__ bias1,
                                                    const float* __restrict__ bias2,
                                                    int M, int N, int K) {
    __shared__ unsigned short As[128 * 64];
    __shared__ unsigned short Bs[128 * 64];
    const int tid = threadIdx.x;
    const int wid = tid >> 6, lane = tid & 63;
    const int wr = wid >> 1, wc = wid & 1;
    const int l15 = lane & 15, l4 = lane >> 4;
    const int m0 = blockIdx.y * 128, n0 = blockIdx.x * 128;

    // staging geometry: chunk q (0..15) covers rows q*8..q*8+7; lane i -> row q*8 + (i>>3), slot (i&7)
    const int rsub = lane >> 3;            // 0..7 (row within chunk)
    const int kslot = (lane & 7) ^ rsub;   // pre-swizzled source k-slot

    f32x4 acc[4][4];
    #pragma unroll
    for (int i = 0; i < 4; ++i)
        #pragma unroll
        for (int j = 0; j < 4; ++j) acc[i][j] = (f32x4){0.f, 0.f, 0.f, 0.f};

    for (int k0 = 0; k0 < K; k0 += 64) {
        #pragma unroll
        for (int c = 0; c < 4; ++c) {
            int q = wid * 4 + c;
            int rowA = m0 + q * 8 + rsub; if (rowA > M - 1) rowA = M - 1;
            gload_lds16(A + (size_t)rowA * K + k0 + kslot * 8, &As[q * 512]);
            int rowB = n0 + q * 8 + rsub;
            gload_lds16(Bt + (size_t)rowB * K + k0 + kslot * 8, &Bs[q * 512]);
        }
        __syncthreads();

        short8 af[2][4], bf[2][4];
        #pragma unroll
        for (int kk = 0; kk < 2; ++kk) {
            #pragma unroll
            for (int mi = 0; mi < 4; ++mi) {
                int row = wr * 64 + mi * 16 + l15;
                af[kk][mi] = *reinterpret_cast<const short8*>(
                    &As[row * 64 + (((kk * 4 + l4) ^ (row & 7)) << 3)]);
            }
            #pragma unroll
            for (int ni = 0; ni < 4; ++ni) {
                int row = wc * 64 + ni * 16 + l15;
                bf[kk][ni] = *reinterpret_cast<const short8*>(
                    &Bs[row * 64 + (((kk * 4 + l4) ^ (row & 7)) << 3)]);
            }
        }
        #pragma unroll
        for (int kk = 0; kk < 2; ++kk)
            #pragma unroll
            for (int mi = 0; mi < 4; ++mi)
                #pragma unroll
                for (int ni = 0; ni < 4; ++ni)
                    acc[mi][ni] = __builtin_amdgcn_mfma_f32_16x16x32_bf16(
                        af[kk][mi], bf[kk][ni], acc[mi][ni], 0, 0, 0);
        __syncthreads();
    }

    float* Cf = (float*)Cv;
    unsigned short* Cb = (unsigned short*)Cv;
    #pragma unroll
    for (int mi = 0; mi < 4; ++mi) {
        int row0 = m0 + wr * 64 + mi * 16 + l4 * 4;
        #pragma unroll
        for (int ni = 0; ni < 4; ++ni) {
            int col = n0 + wc * 64 + ni * 16 + l15;
            float badd = 0.f;
            if (bias1) badd += bias1[col];
            if (bias2) badd += bias2[col];
            f32x4 v = acc[mi][ni];
            #pragma unroll
            for (int i = 0; i < 4; ++i) {
                int row = row0 + i;
                if (row < M) {
                    size_t idx = (size_t)row * N + col;
                    float o = v[i] + badd;
                    if (ACCUM) o += Cf[idx];
                    if (OUTBF) Cb[idx] = f2bf(o);
                    else Cf[idx] = o;
                }
            }
        }
    }
}

// ---------------- attention logit dots (bf16 xp) ----------------
__global__ __launch_bounds__(256) void attn_al(const unsigned short* __restrict__ xp,
                                               const float* __restrict__ a_src,
                                               const float* __restrict__ a_dst,
                                               float* __restrict__ als,
                                               float* __restrict__ ald,
                                               int N, int Ndst) {
    int node = blockIdx.x * 4 + (threadIdx.x >> 6);
    if (node >= N) return;
    int lane = threadIdx.x & 63;
    int h = lane >> 4, c4 = (lane & 15) * 4;
    ushort4 v = *reinterpret_cast<const ushort4*>(&xp[(size_t)node * 256 + lane * 4]);
    float f0 = b2f(v.x), f1 = b2f(v.y), f2 = b2f(v.z), f3 = b2f(v.w);
    const float* as = &a_src[h * 64 + c4];
    const float* ad = &a_dst[h * 64 + c4];
    float ps = f0 * as[0] + f1 * as[1] + f2 * as[2] + f3 * as[3];
    float pd = f0 * ad[0] + f1 * ad[1] + f2 * ad[2] + f3 * ad[3];
    #pragma unroll
    for (int off = 1; off < 16; off <<= 1) {
        ps += __shfl_xor(ps, off, 64);
        pd += __shfl_xor(pd, off, 64);
    }
    if ((lane & 15) == 0) {
        als[(size_t)node * 4 + h] = ps;
        if (node < Ndst) ald[(size_t)node * 4 + h] = pd;
    }
}

// ---------------- fused edge softmax + aggregate: one wave per dst ----------------
__global__ __launch_bounds__(256) void fused_agg(const unsigned short* __restrict__ xp,
                                                 const float* __restrict__ als,
                                                 const float* __restrict__ ald,
                                                 const int* __restrict__ src,
                                                 const int* __restrict__ offs,
                                                 const int* __restrict__ eid,
                                                 float* __restrict__ out, int Ndst) {
    int d = blockIdx.x * 4 + (threadIdx.x >> 6);
    if (d >= Ndst) return;
    int lane = threadIdx.x & 63;
    int beg = offs[d], end = offs[d + 1];
    float4 ad = *reinterpret_cast<const float4*>(&ald[(size_t)d * 4]);

    // pass 1: per-head max over incoming edges
    float4 lm = make_float4(-1e30f, -1e30f, -1e30f, -1e30f);
    for (int i = beg + lane; i < end; i += 64) {
        int e = eid[i]; int s = src[e];
        float4 a = *reinterpret_cast<const float4*>(&als[(size_t)s * 4]);
        float l0 = a.x + ad.x; l0 = l0 > 0.f ? l0 : kNEG * l0;
        float l1 = a.y + ad.y; l1 = l1 > 0.f ? l1 : kNEG * l1;
        float l2 = a.z + ad.z; l2 = l2 > 0.f ? l2 : kNEG * l2;
        float l3 = a.w + ad.w; l3 = l3 > 0.f ? l3 : kNEG * l3;
        lm.x = fmaxf(lm.x, l0); lm.y = fmaxf(lm.y, l1);
        lm.z = fmaxf(lm.z, l2); lm.w = fmaxf(lm.w, l3);
    }
    #pragma unroll
    for (int off = 1; off < 64; off <<= 1) {
        lm.x = fmaxf(lm.x, __shfl_xor(lm.x, off, 64));
        lm.y = fmaxf(lm.y, __shfl_xor(lm.y, off, 64));
        lm.z = fmaxf(lm.z, __shfl_xor(lm.z, off, 64));
        lm.w = fmaxf(lm.w, __shfl_xor(lm.w, off, 64));
    }
    // pass 2: per-head sum of exp
    float4 se = make_float4(0.f, 0.f, 0.f, 0.f);
    for (int i = beg + lane; i < end; i += 64) {
        int e = eid[i]; int s = src[e];
        float4 a = *reinterpret_cast<const float4*>(&als[(size_t)s * 4]);
        float l0 = a.x + ad.x; l0 = l0 > 0.f ? l0 : kNEG * l0;
        float l1 = a.y + ad.y; l1 = l1 > 0.f ? l1 : kNEG * l1;
        float l2 = a.z + ad.z; l2 = l2 > 0.f ? l2 : kNEG * l2;
        float l3 = a.w + ad.w; l3 = l3 > 0.f ? l3 : kNEG * l3;
        se.x += expf(l0 - lm.x); se.y += expf(l1 - lm.y);
        se.z += expf(l2 - lm.z); se.w += expf(l3 - lm.w);
    }
    #pragma unroll
    for (int off = 1; off < 64; off <<= 1) {
        se.x += __shfl_xor(se.x, off, 64);
        se.y += __shfl_xor(se.y, off, 64);
        se.z += __shfl_xor(se.z, off, 64);
        se.w += __shfl_xor(se.w, off, 64);
    }
    // per-lane head-scalar selects
    int h = lane >> 4;
    float mh  = (h == 0) ? lm.x : (h == 1) ? lm.y : (h == 2) ? lm.z : lm.w;
    float sh  = (h == 0) ? se.x : (h == 1) ? se.y : (h == 2) ? se.z : se.w;
    float adh = (h == 0) ? ad.x : (h == 1) ? ad.y : (h == 2) ? ad.z : ad.w;
    float invh = 1.f / (sh + 1e-16f);

    // pass 3: aggregate (lane owns 4 channels)
    float a0 = 0.f, a1 = 0.f, a2 = 0.f, a3 = 0.f;
    for (int i = beg; i < end; ++i) {
        int e = eid[i]; int s = src[e];
        float l = als[(size_t)s * 4 + h] + adh;
        l = l > 0.f ? l : kNEG * l;
        float alpha = expf(l - mh) * invh;
        ushort4 xv = *reinterpret_cast<const ushort4*>(&xp[(size_t)s * 256 + lane * 4]);
        a0 = fmaf(alpha, b2f(xv.x), a0);
        a1 = fmaf(alpha, b2f(xv.y), a1);
        a2 = fmaf(alpha, b2f(xv.z), a2);
        a3 = fmaf(alpha, b2f(xv.w), a3);
    }
    *reinterpret_cast<float4*>(&out[(size_t)d * 256 + lane * 4]) =
        make_float4(a0, a1, a2, a3);
}

// ---------------- BN stats & apply ----------------
__global__ __launch_bounds__(256) void bn_stats(const float* __restrict__ X,
                                                float* __restrict__ stats, int M) {
    int c = threadIdx.x;
    float s = 0.f, sq = 0.f;
    for (int r = blockIdx.x; r < M; r += gridDim.x) {
        float v = X[(size_t)r * 256 + c];
        s += v;
        sq += v * v;
    }
    atomicAdd(&stats[c], s);
    atomicAdd(&stats[256 + c], sq);
}

// ACT: 0 = ELU, 1 = ReLU. OUTBF: write bf16 to out, else f32 (may alias X).
template <int ACT, bool OUTBF>
__global__ __launch_bounds__(256) void bn_apply(const float* __restrict__ X,
                                                const float* __restrict__ stats,
                                                const float* __restrict__ gamma,
                                                const float* __restrict__ beta,
                                                void* __restrict__ out, int M) {
    int row = blockIdx.x;
    int c = threadIdx.x;
    float mu = stats[c] / (float)M;
    float var = stats[256 + c] / (float)M - mu * mu;
    float sc = rsqrtf(var + kEPS) * gamma[c];
    float sh = beta[c];
    size_t idx = (size_t)row * 256 + c;
    float v = (X[idx] - mu) * sc + sh;
    if (ACT == 0) v = v > 0.f ? v : expm1f(v);
    else v = fmaxf(v, 0.f);
    if (OUTBF) ((unsigned short*)out)[idx] = f2bf(v);
    else ((float*)out)[idx] = v;
}

// ---------------- fp32 tiled GEMM (kept for final N=47 head) ----------------
template <bool ACCUM>
__global__ __launch_bounds__(256) void gemm64(const float* __restrict__ A,
                                              const float* __restrict__ B,
                                              float* __restrict__ Cmat,
                                              const float* __restrict__ bias1,
                                              const float* __restrict__ bias2,
                                              int M, int N, int K) {
    __shared__ float As[32][68];
    __shared__ float Bs[32][68];
    const int tid = threadIdx.x;
    const int tx = tid & 15, ty = tid >> 4;
    const int m0 = blockIdx.y * 64, n0 = blockIdx.x * 64;
    float acc[4][4] = {};

    for (int k0 = 0; k0 < K; k0 += 32) {
        #pragma unroll
        for (int t = 0; t < 2; ++t) {
            int i = tid + t * 256;
            int row = i >> 3;
            int kq = (i & 7) << 2;
            float4 v = make_float4(0.f, 0.f, 0.f, 0.f);
            int gr = m0 + row;
            if (gr < M) v = *reinterpret_cast<const float4*>(&A[(size_t)gr * K + k0 + kq]);
            As[kq + 0][row] = v.x; As[kq + 1][row] = v.y;
            As[kq + 2][row] = v.z; As[kq + 3][row] = v.w;
        }
        #pragma unroll
        for (int t = 0; t < 2; ++t) {
            int i = tid + t * 256;
            int kr = i >> 4;
            int cq = (i & 15) << 2;
            #pragma unroll
            for (int j = 0; j < 4; ++j) {
                int gc = n0 + cq + j;
                Bs[kr][cq + j] = (gc < N) ? B[(size_t)(k0 + kr) * N + gc] : 0.f;
            }
        }
        __syncthreads();
        #pragma unroll
        for (int kk = 0; kk < 32; ++kk) {
            float4 a4 = *reinterpret_cast<const float4*>(&As[kk][ty << 2]);
            float4 b4 = *reinterpret_cast<const float4*>(&Bs[kk][tx << 2]);
            float a[4] = {a4.x, a4.y, a4.z, a4.w};
            float b[4] = {b4.x, b4.y, b4.z, b4.w};
            #pragma unroll
            for (int i2 = 0; i2 < 4; ++i2)
                #pragma unroll
                for (int j = 0; j < 4; ++j)
                    acc[i2][j] = fmaf(a[i2], b[j], acc[i2][j]);
        }
        __syncthreads();
    }

    #pragma unroll
    for (int i2 = 0; i2 < 4; ++i2) {
        int row = m0 + (ty << 2) + i2;
        if (row >= M) continue;
        #pragma unroll
        for (int j = 0; j < 4; ++j) {
            int col = n0 + (tx << 2) + j;
            if (col >= N) continue;
            float v = acc[i2][j];
            if (bias1) v += bias1[col];
            if (bias2) v += bias2[col];
            size_t idx = (size_t)row * N + col;
            if (ACCUM) v += Cmat[idx];
            Cmat[idx] = v;
        }
    }
}

extern "C" void kernel_launch(void* const* d_in, const int* in_sizes, int n_in,
                              void* d_out, int out_size, void* d_ws, size_t ws_size,
                              hipStream_t stream) {
    (void)in_sizes; (void)n_in; (void)out_size; (void)ws_size;

    const float* x      = (const float*)d_in[0];
    const int*   src1   = (const int*)d_in[1];
    const int*   dst1   = (const int*)d_in[2];
    const int*   src2   = (const int*)d_in[3];
    const int*   dst2   = (const int*)d_in[4];
    const float* W1     = (const float*)d_in[5];
    const float* a_src1 = (const float*)d_in[6];
    const float* a_dst1 = (const float*)d_in[7];
    const float* b1     = (const float*)d_in[8];
    const float* Wsk1   = (const float*)d_in[9];
    const float* bsk1   = (const float*)d_in[10];
    const float* g1     = (const float*)d_in[11];
    const float* be1    = (const float*)d_in[12];
    const float* W2     = (const float*)d_in[13];
    const float* a_src2 = (const float*)d_in[14];
    const float* a_dst2 = (const float*)d_in[15];
    const float* b2     = (const float*)d_in[16];
    const float* Wsk2   = (const float*)d_in[17];
    const float* bsk2   = (const float*)d_in[18];
    const float* g2     = (const float*)d_in[19];
    const float* be2    = (const float*)d_in[20];
    const float* Wm1    = (const float*)d_in[21];
    const float* bm1    = (const float*)d_in[22];
    const float* gm     = (const float*)d_in[23];
    const float* bem    = (const float*)d_in[24];
    const float* Wm2    = (const float*)d_in[25];
    const float* bm2    = (const float*)d_in[26];

    // ---- workspace layout (float units; all chunks 16B-aligned) ----
    float* ws = (float*)d_ws;
    size_t off = 0;
    auto alloc = [&](size_t n) { float* p = ws + off; off += n; return p; };
    unsigned short* xb  = (unsigned short*)alloc((size_t)kN0 * 128 / 2);   // x bf16 [N0][128]
    unsigned short* xp1 = (unsigned short*)alloc((size_t)kN0 * 256 / 2);   // bf16 [N0][256]; reused as xp2
    float* h1           = alloc((size_t)kN1 * 256);
    unsigned short* h1b = (unsigned short*)alloc((size_t)kN1 * 256 / 2);
    float* h2           = alloc((size_t)kN2 * 256);
    unsigned short* h2b = (unsigned short*)alloc((size_t)kN2 * 256 / 2);
    float* h3           = alloc((size_t)kN2 * 256);
    unsigned short* W1t   = (unsigned short*)alloc(128 * 256 / 2);
    unsigned short* Wsk1t = (unsigned short*)alloc(128 * 256 / 2);
    unsigned short* W2t   = (unsigned short*)alloc(256 * 256 / 2);
    unsigned short* Wsk2t = (unsigned short*)alloc(256 * 256 / 2);
    unsigned short* Wm1t  = (unsigned short*)alloc(256 * 256 / 2);
    float* als1 = alloc((size_t)kN0 * 4);
    float* ald1 = alloc((size_t)kN1 * 4);
    float* als2 = alloc((size_t)kN1 * 4);
    float* ald2 = alloc((size_t)kN2 * 4);
    float* stats = alloc(1536);
    float* stats1 = stats, *stats2 = stats + 512, *stats3 = stats + 1024;
    int* eid1   = (int*)alloc(kE1);
    int* offs1  = (int*)alloc(kN1 + 4);
    int* cnt1   = (int*)alloc(kN1);
    int* bsum1  = (int*)alloc(128);
    int* bscan1 = (int*)alloc(128);
    int* eid2   = (int*)alloc(kE2);
    int* offs2  = (int*)alloc(kN2 + 4);
    int* cnt2   = (int*)alloc(kN2);
    int* bsum2  = (int*)alloc(128);
    int* bscan2 = (int*)alloc(128);
    unsigned short* xp2 = xp1;

    hipStream_t st = stream;
    const int nb1 = (kN1 + 1023) / 1024;
    const int nb2 = (kN2 + 1023) / 1024;

    // ---- converts ----
    conv_bf16<<<(kN0 * 128 / 8 + 255) / 256, 256, 0, st>>>(x, xb, kN0 * 128);
    transp_w<<<1, 256, 0, st>>>(W1, W1t, 128, 256);
    transp_w<<<1, 256, 0, st>>>(Wsk1, Wsk1t, 128, 256);
    transp_w<<<1, 256, 0, st>>>(W2, W2t, 256, 256);
    transp_w<<<1, 256, 0, st>>>(Wsk2, Wsk2t, 256, 256);
    transp_w<<<1, 256, 0, st>>>(Wm1, Wm1t, 256, 256);

    // ---- init ----
    zero_f32<<<6, 256, 0, st>>>(stats, 1536);
    zero_f32<<<(kN1 + 255) / 256, 256, 0, st>>>((float*)cnt1, kN1);
    zero_f32<<<(kN2 + 255) / 256, 256, 0, st>>>((float*)cnt2, kN2);

    // ---- CSR builds ----
    hist_dst<<<(kE1 + 255) / 256, 256, 0, st>>>(dst1, cnt1, kE1);
    scan_block<<<nb1, 256, 0, st>>>(cnt1, kN1, offs1, bsum1);
    scan_bsums<<<1, 256, 0, st>>>(bsum1, bscan1, nb1);
    scan_add<<<(kN1 + 255) / 256, 256, 0, st>>>(offs1, bscan1, cnt1, kN1);
    zero_f32<<<(kN1 + 255) / 256, 256, 0, st>>>((float*)cnt1, kN1);
    csr_scatter<<<(kE1 + 255) / 256, 256, 0, st>>>(dst1, offs1, cnt1, eid1, kE1);

    hist_dst<<<(kE2 + 255) / 256, 256, 0, st>>>(dst2, cnt2, kE2);
    scan_block<<<nb2, 256, 0, st>>>(cnt2, kN2, offs2, bsum2);
    scan_bsums<<<1, 256, 0, st>>>(bsum2, bscan2, nb2);
    scan_add<<<(kN2 + 255) / 256, 256, 0, st>>>(offs2, bscan2, cnt2, kN2);
    zero_f32<<<(kN2 + 255) / 256, 256, 0, st>>>((float*)cnt2, kN2);
    csr_scatter<<<(kE2 + 255) / 256, 256, 0, st>>>(dst2, offs2, cnt2, eid2, kE2);

    // ================= layer 1 =================
    mfma_gemm_bt<true, false><<<dim3(2, (kN0 + 127) / 128), 256, 0, st>>>(
        xb, W1t, xp1, nullptr, nullptr, kN0, 256, 128);
    attn_al<<<(kN0 + 3) / 4, 256, 0, st>>>(xp1, a_src1, a_dst1, als1, ald1, kN0, kN1);
    fused_agg<<<(kN1 + 3) / 4, 256, 0, st>>>(xp1, als1, ald1, src1, offs1, eid1, h1, kN1);
    mfma_gemm_bt<false, true><<<dim3(2, (kN1 + 127) / 128), 256, 0, st>>>(
        xb, Wsk1t, h1, b1, bsk1, kN1, 256, 128);
    bn_stats<<<256, 256, 0, st>>>(h1, stats1, kN1);
    bn_apply<0, true><<<kN1, 256, 0, st>>>(h1, stats1, g1, be1, h1b, kN1);

    // ================= layer 2 =================
    mfma_gemm_bt<true, false><<<dim3(2, (kN1 + 127) / 128), 256, 0, st>>>(
        h1b, W2t, xp2, nullptr, nullptr, kN1, 256, 256);
    attn_al<<<(kN1 + 3) / 4, 256, 0, st>>>(xp2, a_src2, a_dst2, als2, ald2, kN1, kN2);
    fused_agg<<<(kN2 + 3) / 4, 256, 0, st>>>(xp2, als2, ald2, src2, offs2, eid2, h2, kN2);
    mfma_gemm_bt<false, true><<<dim3(2, (kN2 + 127) / 128), 256, 0, st>>>(
        h1b, Wsk2t, h2, b2, bsk2, kN2, 256, 256);
    bn_stats<<<256, 256, 0, st>>>(h2, stats2, kN2);
    bn_apply<0, true><<<kN2, 256, 0, st>>>(h2, stats2, g2, be2, h2b, kN2);

    // ================= MLP head =================
    mfma_gemm_bt<false, false><<<dim3(2, (kN2 + 127) / 128), 256, 0, st>>>(
        h2b, Wm1t, h3, bm1, nullptr, kN2, 256, 256);
    bn_stats<<<256, 256, 0, st>>>(h3, stats3, kN2);
    bn_apply<1, false><<<kN2, 256, 0, st>>>(h3, stats3, gm, bem, h3, kN2);
    gemm64<false><<<dim3(1, (kN2 + 63) / 64), 256, 0, st>>>(
        h3, Wm2, (float*)d_out, bm2, nullptr, kN2, kOUT, 256);
}

// Round 5
// 860.024 us; speedup vs baseline: 6.7609x; 1.8592x over previous
//
#include <hip/hip_runtime.h>
#include <math.h>

// Problem constants (fixed by the reference)
constexpr int kN0 = 400000, kN1 = 100000, kN2 = 20000;
constexpr int kE1 = 1000000, kE2 = 200000;
constexpr int kIN = 128, kHID = 256, kOUT = 47;
constexpr float kEPS = 1e-5f, kNEG = 0.2f;

#define DEV static __device__ __forceinline__

typedef __attribute__((ext_vector_type(8))) short short8;
typedef __attribute__((ext_vector_type(4))) float f32x4;

DEV float b2f(unsigned short u) { return __uint_as_float(((unsigned)u) << 16); }
DEV unsigned short f2bf(float f) {
    unsigned u = __float_as_uint(f);
    unsigned r = (u + 0x7fffu + ((u >> 16) & 1u)) >> 16;   // RNE
    return (unsigned short)r;
}

DEV void gload_lds16(const void* g, void* l) {
    __builtin_amdgcn_global_load_lds(
        (const __attribute__((address_space(1))) void*)g,
        (__attribute__((address_space(3))) void*)l, 16, 0, 0);
}

// ---------------- utility ----------------
__global__ void zero_f32(float* __restrict__ p, int n) {
    int i = blockIdx.x * blockDim.x + threadIdx.x;
    int st = gridDim.x * blockDim.x;
    for (; i < n; i += st) p[i] = 0.f;
}

// f32 -> bf16 bulk convert (n multiple of 8), grid-stride
__global__ __launch_bounds__(256) void conv_bf16(const float* __restrict__ in,
                                                 unsigned short* __restrict__ out, int n) {
    int st = gridDim.x * blockDim.x;
    for (int t = blockIdx.x * blockDim.x + threadIdx.x; t * 8 < n; t += st) {
        int i = t * 8;
        float4 v0 = *reinterpret_cast<const float4*>(&in[i]);
        float4 v1 = *reinterpret_cast<const float4*>(&in[i + 4]);
        ushort4 o0, o1;
        o0.x = f2bf(v0.x); o0.y = f2bf(v0.y); o0.z = f2bf(v0.z); o0.w = f2bf(v0.w);
        o1.x = f2bf(v1.x); o1.y = f2bf(v1.y); o1.z = f2bf(v1.z); o1.w = f2bf(v1.w);
        *reinterpret_cast<ushort4*>(&out[i]) = o0;
        *reinterpret_cast<ushort4*>(&out[i + 4]) = o1;
    }
}

// W[K][N] f32 -> Wt[N][K] bf16, element-parallel (K = power of 2, kshift = log2 K)
__global__ void transp_w_par(const float* __restrict__ W, unsigned short* __restrict__ Wt,
                             int kshift, int N) {
    int i = blockIdx.x * blockDim.x + threadIdx.x;
    int K = 1 << kshift;
    if (i >= N * K) return;
    int n = i >> kshift, k = i & (K - 1);
    Wt[i] = f2bf(W[(size_t)k * N + n]);
}

// ================= CSR build =================
__global__ void hist_dst(const int* __restrict__ dst, int* __restrict__ counts, int E) {
    int e = blockIdx.x * blockDim.x + threadIdx.x;
    if (e < E) atomicAdd(&counts[dst[e]], 1);
}

__global__ __launch_bounds__(256) void scan_block(const int* __restrict__ counts, int n,
                                                  int* __restrict__ offs, int* __restrict__ bsum) {
    __shared__ int sh[256];
    int tid = threadIdx.x;
    int base = blockIdx.x * 1024 + tid * 4;
    int c0 = (base + 0 < n) ? counts[base + 0] : 0;
    int c1 = (base + 1 < n) ? counts[base + 1] : 0;
    int c2 = (base + 2 < n) ? counts[base + 2] : 0;
    int c3 = (base + 3 < n) ? counts[base + 3] : 0;
    int tot = c0 + c1 + c2 + c3;
    sh[tid] = tot;
    __syncthreads();
    for (int o = 1; o < 256; o <<= 1) {
        int t = (tid >= o) ? sh[tid - o] : 0;
        __syncthreads();
        sh[tid] += t;
        __syncthreads();
    }
    int excl = sh[tid] - tot;
    if (base + 0 < n) offs[base + 0] = excl;
    if (base + 1 < n) offs[base + 1] = excl + c0;
    if (base + 2 < n) offs[base + 2] = excl + c0 + c1;
    if (base + 3 < n) offs[base + 3] = excl + c0 + c1 + c2;
    if (tid == 255) bsum[blockIdx.x] = sh[255];
}

__global__ __launch_bounds__(256) void scan_bsums(const int* __restrict__ bsum,
                                                  int* __restrict__ bscan, int nb) {
    __shared__ int sh[256];
    int tid = threadIdx.x;
    int v = (tid < nb) ? bsum[tid] : 0;
    sh[tid] = v;
    __syncthreads();
    for (int o = 1; o < 256; o <<= 1) {
        int t = (tid >= o) ? sh[tid - o] : 0;
        __syncthreads();
        sh[tid] += t;
        __syncthreads();
    }
    if (tid < nb) bscan[tid] = sh[tid] - v;
}

__global__ void scan_add(int* __restrict__ offs, const int* __restrict__ bscan,
                         const int* __restrict__ counts, int n) {
    int i = blockIdx.x * blockDim.x + threadIdx.x;
    if (i < n) {
        int v = offs[i] + bscan[i >> 10];
        offs[i] = v;
        if (i == n - 1) offs[n] = v + counts[i];
    }
}

// store src node id directly (drops the eid indirection from the hot gather loop)
__global__ void csr_scatter(const int* __restrict__ dst, const int* __restrict__ src,
                            const int* __restrict__ offs,
                            int* __restrict__ cur, int* __restrict__ srcs, int E) {
    int e = blockIdx.x * blockDim.x + threadIdx.x;
    if (e >= E) return;
    int d = dst[e];
    int pos = offs[d] + atomicAdd(&cur[d], 1);
    srcs[pos] = src[e];
}

// ================= bf16 MFMA GEMM =================
// C[M][N] (+)= A[M][K]bf16 @ Bt[N][K]bf16^T (+ bias1 + bias2), f32 math.
// BM=BN=128, BK=64, 256 threads = 4 waves (2x2), each wave 64x64 (4x4 frags of 16x16x32).
// STATS: accumulate per-column sum/sumsq of the stored output into stats[0..255],stats[256..511].
template <bool OUTBF, bool ACCUM, bool STATS>
__global__ __launch_bounds__(256) void mfma_gemm_bt(const unsigned short* __restrict__ A,
                                                    const unsigned short* __restrict__ Bt,
                                                    void* __restrict__ Cv,
                                                    const float* __restrict__ bias1,
                                                    const float* __restrict__ bias2,
                                                    float* __restrict__ stats,
                                                    int M, int N, int K) {
    __shared__ unsigned short As[128 * 64];
    __shared__ unsigned short Bs[128 * 64];
    const int tid = threadIdx.x;
    const int wid = tid >> 6, lane = tid & 63;
    const int wr = wid >> 1, wc = wid & 1;
    const int l15 = lane & 15, l4 = lane >> 4;
    const int m0 = blockIdx.y * 128, n0 = blockIdx.x * 128;

    const int rsub = lane >> 3;            // 0..7 (row within chunk)
    const int kslot = (lane & 7) ^ rsub;   // pre-swizzled source k-slot

    f32x4 acc[4][4];
    #pragma unroll
    for (int i = 0; i < 4; ++i)
        #pragma unroll
        for (int j = 0; j < 4; ++j) acc[i][j] = (f32x4){0.f, 0.f, 0.f, 0.f};

    for (int k0 = 0; k0 < K; k0 += 64) {
        #pragma unroll
        for (int c = 0; c < 4; ++c) {
            int q = wid * 4 + c;
            int rowA = m0 + q * 8 + rsub; if (rowA > M - 1) rowA = M - 1;
            gload_lds16(A + (size_t)rowA * K + k0 + kslot * 8, &As[q * 512]);
            int rowB = n0 + q * 8 + rsub;
            gload_lds16(Bt + (size_t)rowB * K + k0 + kslot * 8, &Bs[q * 512]);
        }
        __syncthreads();

        short8 af[2][4], bf[2][4];
        #pragma unroll
        for (int kk = 0; kk < 2; ++kk) {
            #pragma unroll
            for (int mi = 0; mi < 4; ++mi) {
                int row = wr * 64 + mi * 16 + l15;
                af[kk][mi] = *reinterpret_cast<const short8*>(
                    &As[row * 64 + (((kk * 4 + l4) ^ (row & 7)) << 3)]);
            }
            #pragma unroll
            for (int ni = 0; ni < 4; ++ni) {
                int row = wc * 64 + ni * 16 + l15;
                bf[kk][ni] = *reinterpret_cast<const short8*>(
                    &Bs[row * 64 + (((kk * 4 + l4) ^ (row & 7)) << 3)]);
            }
        }
        #pragma unroll
        for (int kk = 0; kk < 2; ++kk)
            #pragma unroll
            for (int mi = 0; mi < 4; ++mi)
                #pragma unroll
                for (int ni = 0; ni < 4; ++ni)
                    acc[mi][ni] = __builtin_amdgcn_mfma_f32_16x16x32_bf16(
                        af[kk][mi], bf[kk][ni], acc[mi][ni], 0, 0, 0);
        __syncthreads();
    }

    float* Cf = (float*)Cv;
    unsigned short* Cb = (unsigned short*)Cv;
    float csum[4] = {0.f, 0.f, 0.f, 0.f}, csq[4] = {0.f, 0.f, 0.f, 0.f};
    #pragma unroll
    for (int mi = 0; mi < 4; ++mi) {
        int row0 = m0 + wr * 64 + mi * 16 + l4 * 4;
        #pragma unroll
        for (int ni = 0; ni < 4; ++ni) {
            int col = n0 + wc * 64 + ni * 16 + l15;
            float badd = 0.f;
            if (bias1) badd += bias1[col];
            if (bias2) badd += bias2[col];
            f32x4 v = acc[mi][ni];
            #pragma unroll
            for (int i = 0; i < 4; ++i) {
                int row = row0 + i;
                if (row < M) {
                    size_t idx = (size_t)row * N + col;
                    float o = v[i] + badd;
                    if (ACCUM) o += Cf[idx];
                    if (STATS) { csum[ni] += o; csq[ni] += o * o; }
                    if (OUTBF) Cb[idx] = f2bf(o);
                    else Cf[idx] = o;
                }
            }
        }
    }
    if (STATS) {
        #pragma unroll
        for (int ni = 0; ni < 4; ++ni) {
            float s = csum[ni], q = csq[ni];
            s += __shfl_xor(s, 16, 64); q += __shfl_xor(q, 16, 64);
            s += __shfl_xor(s, 32, 64); q += __shfl_xor(q, 32, 64);
            if (l4 == 0) {
                int col = n0 + wc * 64 + ni * 16 + l15;
                atomicAdd(&stats[col], s);
                atomicAdd(&stats[256 + col], q);
            }
        }
    }
}

// ---------------- attention logit dots (bf16 xp) ----------------
__global__ __launch_bounds__(256) void attn_al(const unsigned short* __restrict__ xp,
                                               const float* __restrict__ a_src,
                                               const float* __restrict__ a_dst,
                                               float* __restrict__ als,
                                               float* __restrict__ ald,
                                               int N, int Ndst) {
    int node = blockIdx.x * 4 + (threadIdx.x >> 6);
    if (node >= N) return;
    int lane = threadIdx.x & 63;
    int h = lane >> 4, c4 = (lane & 15) * 4;
    ushort4 v = *reinterpret_cast<const ushort4*>(&xp[(size_t)node * 256 + lane * 4]);
    float f0 = b2f(v.x), f1 = b2f(v.y), f2 = b2f(v.z), f3 = b2f(v.w);
    const float* as = &a_src[h * 64 + c4];
    const float* ad = &a_dst[h * 64 + c4];
    float ps = f0 * as[0] + f1 * as[1] + f2 * as[2] + f3 * as[3];
    float pd = f0 * ad[0] + f1 * ad[1] + f2 * ad[2] + f3 * ad[3];
    #pragma unroll
    for (int off = 1; off < 16; off <<= 1) {
        ps += __shfl_xor(ps, off, 64);
        pd += __shfl_xor(pd, off, 64);
    }
    if ((lane & 15) == 0) {
        als[(size_t)node * 4 + h] = ps;
        if (node < Ndst) ald[(size_t)node * 4 + h] = pd;
    }
}

// ---------------- fused edge softmax + aggregate: one wave per dst ----------------
__global__ __launch_bounds__(256) void fused_agg(const unsigned short* __restrict__ xp,
                                                 const float* __restrict__ als,
                                                 const float* __restrict__ ald,
                                                 const int* __restrict__ srcs,
                                                 const int* __restrict__ offs,
                                                 float* __restrict__ out, int Ndst) {
    int d = blockIdx.x * 4 + (threadIdx.x >> 6);
    if (d >= Ndst) return;
    int lane = threadIdx.x & 63;
    int beg = offs[d], end = offs[d + 1];
    float4 ad = *reinterpret_cast<const float4*>(&ald[(size_t)d * 4]);

    // pass 1: per-head max over incoming edges
    float4 lm = make_float4(-1e30f, -1e30f, -1e30f, -1e30f);
    for (int i = beg + lane; i < end; i += 64) {
        int s = srcs[i];
        float4 a = *reinterpret_cast<const float4*>(&als[(size_t)s * 4]);
        float l0 = a.x + ad.x; l0 = l0 > 0.f ? l0 : kNEG * l0;
        float l1 = a.y + ad.y; l1 = l1 > 0.f ? l1 : kNEG * l1;
        float l2 = a.z + ad.z; l2 = l2 > 0.f ? l2 : kNEG * l2;
        float l3 = a.w + ad.w; l3 = l3 > 0.f ? l3 : kNEG * l3;
        lm.x = fmaxf(lm.x, l0); lm.y = fmaxf(lm.y, l1);
        lm.z = fmaxf(lm.z, l2); lm.w = fmaxf(lm.w, l3);
    }
    #pragma unroll
    for (int off = 1; off < 64; off <<= 1) {
        lm.x = fmaxf(lm.x, __shfl_xor(lm.x, off, 64));
        lm.y = fmaxf(lm.y, __shfl_xor(lm.y, off, 64));
        lm.z = fmaxf(lm.z, __shfl_xor(lm.z, off, 64));
        lm.w = fmaxf(lm.w, __shfl_xor(lm.w, off, 64));
    }
    // pass 2: per-head sum of exp
    float4 se = make_float4(0.f, 0.f, 0.f, 0.f);
    for (int i = beg + lane; i < end; i += 64) {
        int s = srcs[i];
        float4 a = *reinterpret_cast<const float4*>(&als[(size_t)s * 4]);
        float l0 = a.x + ad.x; l0 = l0 > 0.f ? l0 : kNEG * l0;
        float l1 = a.y + ad.y; l1 = l1 > 0.f ? l1 : kNEG * l1;
        float l2 = a.z + ad.z; l2 = l2 > 0.f ? l2 : kNEG * l2;
        float l3 = a.w + ad.w; l3 = l3 > 0.f ? l3 : kNEG * l3;
        se.x += expf(l0 - lm.x); se.y += expf(l1 - lm.y);
        se.z += expf(l2 - lm.z); se.w += expf(l3 - lm.w);
    }
    #pragma unroll
    for (int off = 1; off < 64; off <<= 1) {
        se.x += __shfl_xor(se.x, off, 64);
        se.y += __shfl_xor(se.y, off, 64);
        se.z += __shfl_xor(se.z, off, 64);
        se.w += __shfl_xor(se.w, off, 64);
    }
    // per-lane head scalars
    int h = lane >> 4;
    float mh  = (h == 0) ? lm.x : (h == 1) ? lm.y : (h == 2) ? lm.z : lm.w;
    float sh  = (h == 0) ? se.x : (h == 1) ? se.y : (h == 2) ? se.z : se.w;
    float adh = (h == 0) ? ad.x : (h == 1) ? ad.y : (h == 2) ? ad.z : ad.w;
    float invh = 1.f / (sh + 1e-16f);

    // pass 3: aggregate, 4-way unrolled for memory-level parallelism
    float a0 = 0.f, a1 = 0.f, a2 = 0.f, a3 = 0.f;
    int i = beg;
    for (; i + 4 <= end; i += 4) {
        int s0 = srcs[i + 0], s1 = srcs[i + 1], s2 = srcs[i + 2], s3 = srcs[i + 3];
        float l0 = als[(size_t)s0 * 4 + h] + adh;
        float l1 = als[(size_t)s1 * 4 + h] + adh;
        float l2 = als[(size_t)s2 * 4 + h] + adh;
        float l3 = als[(size_t)s3 * 4 + h] + adh;
        ushort4 x0 = *reinterpret_cast<const ushort4*>(&xp[(size_t)s0 * 256 + lane * 4]);
        ushort4 x1 = *reinterpret_cast<const ushort4*>(&xp[(size_t)s1 * 256 + lane * 4]);
        ushort4 x2 = *reinterpret_cast<const ushort4*>(&xp[(size_t)s2 * 256 + lane * 4]);
        ushort4 x3 = *reinterpret_cast<const ushort4*>(&xp[(size_t)s3 * 256 + lane * 4]);
        l0 = l0 > 0.f ? l0 : kNEG * l0; float w0 = expf(l0 - mh) * invh;
        l1 = l1 > 0.f ? l1 : kNEG * l1; float w1 = expf(l1 - mh) * invh;
        l2 = l2 > 0.f ? l2 : kNEG * l2; float w2 = expf(l2 - mh) * invh;
        l3 = l3 > 0.f ? l3 : kNEG * l3; float w3 = expf(l3 - mh) * invh;
        a0 = fmaf(w0, b2f(x0.x), a0); a1 = fmaf(w0, b2f(x0.y), a1);
        a2 = fmaf(w0, b2f(x0.z), a2); a3 = fmaf(w0, b2f(x0.w), a3);
        a0 = fmaf(w1, b2f(x1.x), a0); a1 = fmaf(w1, b2f(x1.y), a1);
        a2 = fmaf(w1, b2f(x1.z), a2); a3 = fmaf(w1, b2f(x1.w), a3);
        a0 = fmaf(w2, b2f(x2.x), a0); a1 = fmaf(w2, b2f(x2.y), a1);
        a2 = fmaf(w2, b2f(x2.z), a2); a3 = fmaf(w2, b2f(x2.w), a3);
        a0 = fmaf(w3, b2f(x3.x), a0); a1 = fmaf(w3, b2f(x3.y), a1);
        a2 = fmaf(w3, b2f(x3.z), a2); a3 = fmaf(w3, b2f(x3.w), a3);
    }
    for (; i < end; ++i) {
        int s = srcs[i];
        float l = als[(size_t)s * 4 + h] + adh;
        l = l > 0.f ? l : kNEG * l;
        float w = expf(l - mh) * invh;
        ushort4 xv = *reinterpret_cast<const ushort4*>(&xp[(size_t)s * 256 + lane * 4]);
        a0 = fmaf(w, b2f(xv.x), a0);
        a1 = fmaf(w, b2f(xv.y), a1);
        a2 = fmaf(w, b2f(xv.z), a2);
        a3 = fmaf(w, b2f(xv.w), a3);
    }
    *reinterpret_cast<float4*>(&out[(size_t)d * 256 + lane * 4]) =
        make_float4(a0, a1, a2, a3);
}

// ---------------- BN apply (stats precomputed in GEMM epilogue) ----------------
// ACT: 0 = ELU, 1 = ReLU. OUTBF: write bf16 to out, else f32 (may alias X).
template <int ACT, bool OUTBF>
__global__ __launch_bounds__(256) void bn_apply(const float* __restrict__ X,
                                                const float* __restrict__ stats,
                                                const float* __restrict__ gamma,
                                                const float* __restrict__ beta,
                                                void* __restrict__ out, int M) {
    int c = threadIdx.x;
    float mu = stats[c] / (float)M;
    float var = stats[256 + c] / (float)M - mu * mu;
    float sc = rsqrtf(var + kEPS) * gamma[c];
    float sh = beta[c];
    for (int row = blockIdx.x; row < M; row += gridDim.x) {
        size_t idx = (size_t)row * 256 + c;
        float v = (X[idx] - mu) * sc + sh;
        if (ACT == 0) v = v > 0.f ? v : expm1f(v);
        else v = fmaxf(v, 0.f);
        if (OUTBF) ((unsigned short*)out)[idx] = f2bf(v);
        else ((float*)out)[idx] = v;
    }
}

// ---------------- fp32 tiled GEMM (final N=47 head) ----------------
template <bool ACCUM>
__global__ __launch_bounds__(256) void gemm64(const float* __restrict__ A,
                                              const float* __restrict__ B,
                                              float* __restrict__ Cmat,
                                              const float* __restrict__ bias1,
                                              const float* __restrict__ bias2,
                                              int M, int N, int K) {
    __shared__ float As[32][68];
    __shared__ float Bs[32][68];
    const int tid = threadIdx.x;
    const int tx = tid & 15, ty = tid >> 4;
    const int m0 = blockIdx.y * 64, n0 = blockIdx.x * 64;
    float acc[4][4] = {};

    for (int k0 = 0; k0 < K; k0 += 32) {
        #pragma unroll
        for (int t = 0; t < 2; ++t) {
            int i = tid + t * 256;
            int row = i >> 3;
            int kq = (i & 7) << 2;
            float4 v = make_float4(0.f, 0.f, 0.f, 0.f);
            int gr = m0 + row;
            if (gr < M) v = *reinterpret_cast<const float4*>(&A[(size_t)gr * K + k0 + kq]);
            As[kq + 0][row] = v.x; As[kq + 1][row] = v.y;
            As[kq + 2][row] = v.z; As[kq + 3][row] = v.w;
        }
        #pragma unroll
        for (int t = 0; t < 2; ++t) {
            int i = tid + t * 256;
            int kr = i >> 4;
            int cq = (i & 15) << 2;
            #pragma unroll
            for (int j = 0; j < 4; ++j) {
                int gc = n0 + cq + j;
                Bs[kr][cq + j] = (gc < N) ? B[(size_t)(k0 + kr) * N + gc] : 0.f;
            }
        }
        __syncthreads();
        #pragma unroll
        for (int kk = 0; kk < 32; ++kk) {
            float4 a4 = *reinterpret_cast<const float4*>(&As[kk][ty << 2]);
            float4 b4 = *reinterpret_cast<const float4*>(&Bs[kk][tx << 2]);
            float a[4] = {a4.x, a4.y, a4.z, a4.w};
            float b[4] = {b4.x, b4.y, b4.z, b4.w};
            #pragma unroll
            for (int i2 = 0; i2 < 4; ++i2)
                #pragma unroll
                for (int j = 0; j < 4; ++j)
                    acc[i2][j] = fmaf(a[i2], b[j], acc[i2][j]);
        }
        __syncthreads();
    }

    #pragma unroll
    for (int i2 = 0; i2 < 4; ++i2) {
        int row = m0 + (ty << 2) + i2;
        if (row >= M) continue;
        #pragma unroll
        for (int j = 0; j < 4; ++j) {
            int col = n0 + (tx << 2) + j;
            if (col >= N) continue;
            float v = acc[i2][j];
            if (bias1) v += bias1[col];
            if (bias2) v += bias2[col];
            size_t idx = (size_t)row * N + col;
            if (ACCUM) v += Cmat[idx];
            Cmat[idx] = v;
        }
    }
}

extern "C" void kernel_launch(void* const* d_in, const int* in_sizes, int n_in,
                              void* d_out, int out_size, void* d_ws, size_t ws_size,
                              hipStream_t stream) {
    (void)in_sizes; (void)n_in; (void)out_size; (void)ws_size;

    const float* x      = (const float*)d_in[0];
    const int*   src1   = (const int*)d_in[1];
    const int*   dst1   = (const int*)d_in[2];
    const int*   src2   = (const int*)d_in[3];
    const int*   dst2   = (const int*)d_in[4];
    const float* W1     = (const float*)d_in[5];
    const float* a_src1 = (const float*)d_in[6];
    const float* a_dst1 = (const float*)d_in[7];
    const float* b1     = (const float*)d_in[8];
    const float* Wsk1   = (const float*)d_in[9];
    const float* bsk1   = (const float*)d_in[10];
    const float* g1     = (const float*)d_in[11];
    const float* be1    = (const float*)d_in[12];
    const float* W2     = (const float*)d_in[13];
    const float* a_src2 = (const float*)d_in[14];
    const float* a_dst2 = (const float*)d_in[15];
    const float* b2     = (const float*)d_in[16];
    const float* Wsk2   = (const float*)d_in[17];
    const float* bsk2   = (const float*)d_in[18];
    const float* g2     = (const float*)d_in[19];
    const float* be2    = (const float*)d_in[20];
    const float* Wm1    = (const float*)d_in[21];
    const float* bm1    = (const float*)d_in[22];
    const float* gm     = (const float*)d_in[23];
    const float* bem    = (const float*)d_in[24];
    const float* Wm2    = (const float*)d_in[25];
    const float* bm2    = (const float*)d_in[26];

    // ---- workspace layout (float units; all chunks 16B-aligned) ----
    float* ws = (float*)d_ws;
    size_t off = 0;
    auto alloc = [&](size_t n) { float* p = ws + off; off += n; return p; };
    unsigned short* xb  = (unsigned short*)alloc((size_t)kN0 * 128 / 2);   // x bf16 [N0][128]
    unsigned short* xp1 = (unsigned short*)alloc((size_t)kN0 * 256 / 2);   // bf16; reused as xp2
    float* h1           = alloc((size_t)kN1 * 256);
    unsigned short* h1b = (unsigned short*)alloc((size_t)kN1 * 256 / 2);
    float* h2           = alloc((size_t)kN2 * 256);
    unsigned short* h2b = (unsigned short*)alloc((size_t)kN2 * 256 / 2);
    float* h3           = alloc((size_t)kN2 * 256);
    unsigned short* W1t   = (unsigned short*)alloc(128 * 256 / 2);
    unsigned short* Wsk1t = (unsigned short*)alloc(128 * 256 / 2);
    unsigned short* W2t   = (unsigned short*)alloc(256 * 256 / 2);
    unsigned short* Wsk2t = (unsigned short*)alloc(256 * 256 / 2);
    unsigned short* Wm1t  = (unsigned short*)alloc(256 * 256 / 2);
    float* als1 = alloc((size_t)kN0 * 4);
    float* ald1 = alloc((size_t)kN1 * 4);
    float* als2 = alloc((size_t)kN1 * 4);
    float* ald2 = alloc((size_t)kN2 * 4);
    // contiguous zero-init region: stats + cnt1 + cur1 + cnt2 + cur2
    float* zreg = alloc(1536 + kN1 + kN1 + kN2 + kN2);
    float* stats = zreg;
    float* stats1 = stats, *stats2 = stats + 512, *stats3 = stats + 1024;
    int* cnt1 = (int*)(zreg + 1536);
    int* cur1 = cnt1 + kN1;
    int* cnt2 = cur1 + kN1;
    int* cur2 = cnt2 + kN2;
    const int nzreg = 1536 + 2 * kN1 + 2 * kN2;
    int* srcs1  = (int*)alloc(kE1);
    int* offs1  = (int*)alloc(kN1 + 4);
    int* bsum1  = (int*)alloc(128);
    int* bscan1 = (int*)alloc(128);
    int* srcs2  = (int*)alloc(kE2);
    int* offs2  = (int*)alloc(kN2 + 4);
    int* bsum2  = (int*)alloc(128);
    int* bscan2 = (int*)alloc(128);
    unsigned short* xp2 = xp1;

    hipStream_t st = stream;
    const int nb1 = (kN1 + 1023) / 1024;
    const int nb2 = (kN2 + 1023) / 1024;

    // ---- converts (parallel) ----
    conv_bf16<<<2048, 256, 0, st>>>(x, xb, kN0 * 128);
    transp_w_par<<<(256 * 128 + 255) / 256, 256, 0, st>>>(W1, W1t, 7, 256);
    transp_w_par<<<(256 * 128 + 255) / 256, 256, 0, st>>>(Wsk1, Wsk1t, 7, 256);
    transp_w_par<<<(256 * 256 + 255) / 256, 256, 0, st>>>(W2, W2t, 8, 256);
    transp_w_par<<<(256 * 256 + 255) / 256, 256, 0, st>>>(Wsk2, Wsk2t, 8, 256);
    transp_w_par<<<(256 * 256 + 255) / 256, 256, 0, st>>>(Wm1, Wm1t, 8, 256);

    // ---- init (single contiguous zero) ----
    zero_f32<<<512, 256, 0, st>>>(zreg, nzreg);

    // ---- CSR builds ----
    hist_dst<<<(kE1 + 255) / 256, 256, 0, st>>>(dst1, cnt1, kE1);
    scan_block<<<nb1, 256, 0, st>>>(cnt1, kN1, offs1, bsum1);
    scan_bsums<<<1, 256, 0, st>>>(bsum1, bscan1, nb1);
    scan_add<<<(kN1 + 255) / 256, 256, 0, st>>>(offs1, bscan1, cnt1, kN1);
    csr_scatter<<<(kE1 + 255) / 256, 256, 0, st>>>(dst1, src1, offs1, cur1, srcs1, kE1);

    hist_dst<<<(kE2 + 255) / 256, 256, 0, st>>>(dst2, cnt2, kE2);
    scan_block<<<nb2, 256, 0, st>>>(cnt2, kN2, offs2, bsum2);
    scan_bsums<<<1, 256, 0, st>>>(bsum2, bscan2, nb2);
    scan_add<<<(kN2 + 255) / 256, 256, 0, st>>>(offs2, bscan2, cnt2, kN2);
    csr_scatter<<<(kE2 + 255) / 256, 256, 0, st>>>(dst2, src2, offs2, cur2, srcs2, kE2);

    // ================= layer 1 =================
    mfma_gemm_bt<true, false, false><<<dim3(2, (kN0 + 127) / 128), 256, 0, st>>>(
        xb, W1t, xp1, nullptr, nullptr, nullptr, kN0, 256, 128);
    attn_al<<<(kN0 + 3) / 4, 256, 0, st>>>(xp1, a_src1, a_dst1, als1, ald1, kN0, kN1);
    fused_agg<<<(kN1 + 3) / 4, 256, 0, st>>>(xp1, als1, ald1, srcs1, offs1, h1, kN1);
    mfma_gemm_bt<false, true, true><<<dim3(2, (kN1 + 127) / 128), 256, 0, st>>>(
        xb, Wsk1t, h1, b1, bsk1, stats1, kN1, 256, 128);
    bn_apply<0, true><<<2048, 256, 0, st>>>(h1, stats1, g1, be1, h1b, kN1);

    // ================= layer 2 =================
    mfma_gemm_bt<true, false, false><<<dim3(2, (kN1 + 127) / 128), 256, 0, st>>>(
        h1b, W2t, xp2, nullptr, nullptr, nullptr, kN1, 256, 256);
    attn_al<<<(kN1 + 3) / 4, 256, 0, st>>>(xp2, a_src2, a_dst2, als2, ald2, kN1, kN2);
    fused_agg<<<(kN2 + 3) / 4, 256, 0, st>>>(xp2, als2, ald2, srcs2, offs2, h2, kN2);
    mfma_gemm_bt<false, true, true><<<dim3(2, (kN2 + 127) / 128), 256, 0, st>>>(
        h1b, Wsk2t, h2, b2, bsk2, stats2, kN2, 256, 256);
    bn_apply<0, true><<<2048, 256, 0, st>>>(h2, stats2, g2, be2, h2b, kN2);

    // ================= MLP head =================
    mfma_gemm_bt<false, false, true><<<dim3(2, (kN2 + 127) / 128), 256, 0, st>>>(
        h2b, Wm1t, h3, bm1, nullptr, stats3, kN2, 256, 256);
    bn_apply<1, false><<<2048, 256, 0, st>>>(h3, stats3, gm, bem, h3, kN2);
    gemm64<false><<<dim3(1, (kN2 + 63) / 64), 256, 0, st>>>(
        h3, Wm2, (float*)d_out, bm2, nullptr, kN2, kOUT, 256);
}